// Round 1
// baseline (1871.943 us; speedup 1.0000x reference)
//
#include <hip/hip_runtime.h>
#include <math.h>

#define N_NODES 4096
#define D_IN    128
#define CD2     256   // 2*D
#define NHEADS  4
#define DQDIM   32
#define NCLUST  64

// ---------------------------------------------------------------- combined
__global__ __launch_bounds__(256) void k_combined(const float* __restrict__ x,
                                                  const float* __restrict__ h,
                                                  float* __restrict__ comb) {
  int i = blockIdx.x * blockDim.x + threadIdx.x;   // over N*64 float4
  int n = i >> 6, c = i & 63;
  float4 v;
  if (c < 32) v = ((const float4*)x)[n * 32 + c];
  else        v = ((const float4*)h)[n * 32 + (c - 32)];
  ((float4*)comb)[i] = v;
}

// ---------------------------------------------------------------- GEMM
// out[m][j] = sum_k A[m][k] * W[j][k] + bias[j]   (+ epilogue)
// EPI: 0 = none, 1 = relu, 2 = add resid[m][j]
template <int EPI>
__global__ __launch_bounds__(256) void k_gemm(const float* __restrict__ A,
                                              const float* __restrict__ W,
                                              const float* __restrict__ bias,
                                              const float* __restrict__ resid,
                                              float* __restrict__ out,
                                              int M, int K, int J) {
  __shared__ float As[32][68];   // [k][m], pad 68 keeps 16B align + bank spread
  __shared__ float Ws[32][68];   // [k][j]
  const int t  = threadIdx.x;
  const int mb = blockIdx.x * 64, jb = blockIdx.y * 64;
  const int tm = t & 15, tj = t >> 4;
  float acc[4][4] = {{0.f}};

  for (int kb = 0; kb < K; kb += 32) {
    __syncthreads();
#pragma unroll
    for (int i = 0; i < 2; ++i) {
      int f  = t + i * 256;            // 512 float4 per matrix
      int r  = f >> 3;
      int c4 = (f & 7) << 2;
      float4 a = *(const float4*)&A[(size_t)(mb + r) * K + kb + c4];
      As[c4 + 0][r] = a.x; As[c4 + 1][r] = a.y;
      As[c4 + 2][r] = a.z; As[c4 + 3][r] = a.w;
      float4 w = *(const float4*)&W[(size_t)(jb + r) * K + kb + c4];
      Ws[c4 + 0][r] = w.x; Ws[c4 + 1][r] = w.y;
      Ws[c4 + 2][r] = w.z; Ws[c4 + 3][r] = w.w;
    }
    __syncthreads();
#pragma unroll
    for (int k = 0; k < 32; ++k) {
      float4 a = *(const float4*)&As[k][tm * 4];
      float4 b = *(const float4*)&Ws[k][tj * 4];
      float av[4] = {a.x, a.y, a.z, a.w};
      float bv[4] = {b.x, b.y, b.z, b.w};
#pragma unroll
      for (int i = 0; i < 4; ++i)
#pragma unroll
        for (int j = 0; j < 4; ++j)
          acc[i][j] = fmaf(av[i], bv[j], acc[i][j]);
    }
  }

  float bj[4];
#pragma unroll
  for (int j = 0; j < 4; ++j) bj[j] = bias[jb + tj * 4 + j];
#pragma unroll
  for (int i = 0; i < 4; ++i) {
    size_t m = mb + tm * 4 + i;
    float4 r;
    float* rr = (float*)&r;
#pragma unroll
    for (int j = 0; j < 4; ++j) {
      float v = acc[i][j] + bj[j];
      if (EPI == 1) v = fmaxf(v, 0.f);
      rr[j] = v;
    }
    if (EPI == 2) {
      float4 rs = *(const float4*)&resid[m * J + jb + tj * 4];
      r.x += rs.x; r.y += rs.y; r.z += rs.z; r.w += rs.w;
    }
    *(float4*)&out[m * J + jb + tj * 4] = r;
  }
}

// ---------------------------------------------------------------- flash attention
// q,k layout: [N][H*32] (j = h*32+e). v layout: [N][H*256]. out hp: [N][H*256].
__global__ __launch_bounds__(256) void k_attn(const float* __restrict__ qg,
                                              const float* __restrict__ kg,
                                              const float* __restrict__ vg,
                                              float* __restrict__ hp) {
  const int hd = blockIdx.y;
  const int qb = blockIdx.x * 32;
  const int t  = threadIdx.x;
  __shared__ float Ks[32][36];        // 16B-aligned rows
  __shared__ float Vs[32 * 260];      // stride 260: aligned + conflict-free reads
  __shared__ float Ss[32][33];
  __shared__ float mS[32], lS[32], cS[32];

  const int myq = t & 31;
  float qr[32];
  {
    const float* qp = &qg[(qb + myq) * 128 + hd * 32];
#pragma unroll
    for (int e4 = 0; e4 < 8; ++e4) {
      float4 v = *(const float4*)&qp[e4 * 4];
      qr[e4 * 4 + 0] = v.x; qr[e4 * 4 + 1] = v.y;
      qr[e4 * 4 + 2] = v.z; qr[e4 * 4 + 3] = v.w;
    }
  }
  if (t < 32) { mS[t] = -1e30f; lS[t] = 0.f; }

  float acc0[16], acc1[16];
#pragma unroll
  for (int i = 0; i < 16; ++i) { acc0[i] = 0.f; acc1[i] = 0.f; }

  const int tx = t & 15, ty = t >> 4;
  const float scale = 0.17677669529663687f;   // 1/sqrt(32)

  for (int kb = 0; kb < N_NODES; kb += 32) {
    __syncthreads();
    {   // K tile 32x32
      int r = t >> 3, c4 = (t & 7) << 2;
      float4 kv = *(const float4*)&kg[(kb + r) * 128 + hd * 32 + c4];
      *(float4*)&Ks[r][c4] = kv;
    }
#pragma unroll
    for (int i = 0; i < 8; ++i) {   // V tile 32x256
      int f = t + i * 256;
      int r = f >> 6, c4 = (f & 63) << 2;
      float4 vv = *(const float4*)&vg[(kb + r) * 1024 + hd * 256 + c4];
      *(float4*)&Vs[r * 260 + c4] = vv;
    }
    __syncthreads();
    // scores: 4 per thread; k row broadcast across half-wave
#pragma unroll
    for (int j = 0; j < 4; ++j) {
      int kk = (t >> 5) + 8 * j;
      float s = 0.f;
#pragma unroll
      for (int e4 = 0; e4 < 8; ++e4) {
        float4 k4 = *(const float4*)&Ks[kk][e4 * 4];
        s = fmaf(qr[e4 * 4 + 0], k4.x, s);
        s = fmaf(qr[e4 * 4 + 1], k4.y, s);
        s = fmaf(qr[e4 * 4 + 2], k4.z, s);
        s = fmaf(qr[e4 * 4 + 3], k4.w, s);
      }
      s *= scale;
      s = s > 0.f ? s : 0.2f * s;     // leaky_relu(0.2) before softmax
      Ss[myq][kk] = s;
    }
    __syncthreads();
    // online softmax: 8 threads per query row
    {
      int r = t >> 3, jj = t & 7;
      float sv[4];
      float mx = -1e30f;
#pragma unroll
      for (int i = 0; i < 4; ++i) { sv[i] = Ss[r][jj + 8 * i]; mx = fmaxf(mx, sv[i]); }
      mx = fmaxf(mx, __shfl_xor(mx, 1));
      mx = fmaxf(mx, __shfl_xor(mx, 2));
      mx = fmaxf(mx, __shfl_xor(mx, 4));
      float mold = mS[r];
      float mnew = fmaxf(mold, mx);
      float psum = 0.f;
#pragma unroll
      for (int i = 0; i < 4; ++i) {
        float p = __expf(sv[i] - mnew);
        psum += p;
        Ss[r][jj + 8 * i] = p;
      }
      psum += __shfl_xor(psum, 1);
      psum += __shfl_xor(psum, 2);
      psum += __shfl_xor(psum, 4);
      if (jj == 0) {
        cS[r] = __expf(mold - mnew);
        mS[r] = mnew;
        lS[r] = lS[r] * cS[r] + psum;
      }
    }
    __syncthreads();
    // PV accumulate: thread owns 2 q-rows x 16 dims (tx*4 + 64j)
    {
      float c0 = cS[ty * 2], c1 = cS[ty * 2 + 1];
#pragma unroll
      for (int i = 0; i < 16; ++i) { acc0[i] *= c0; acc1[i] *= c1; }
#pragma unroll
      for (int kk = 0; kk < 32; ++kk) {
        float p0 = Ss[ty * 2][kk], p1 = Ss[ty * 2 + 1][kk];
#pragma unroll
        for (int j = 0; j < 4; ++j) {
          float4 v4 = *(const float4*)&Vs[kk * 260 + tx * 4 + 64 * j];
          acc0[j * 4 + 0] = fmaf(p0, v4.x, acc0[j * 4 + 0]);
          acc0[j * 4 + 1] = fmaf(p0, v4.y, acc0[j * 4 + 1]);
          acc0[j * 4 + 2] = fmaf(p0, v4.z, acc0[j * 4 + 2]);
          acc0[j * 4 + 3] = fmaf(p0, v4.w, acc0[j * 4 + 3]);
          acc1[j * 4 + 0] = fmaf(p1, v4.x, acc1[j * 4 + 0]);
          acc1[j * 4 + 1] = fmaf(p1, v4.y, acc1[j * 4 + 1]);
          acc1[j * 4 + 2] = fmaf(p1, v4.z, acc1[j * 4 + 2]);
          acc1[j * 4 + 3] = fmaf(p1, v4.w, acc1[j * 4 + 3]);
        }
      }
    }
  }
  __syncthreads();
  {
    float r0 = 1.f / lS[ty * 2], r1 = 1.f / lS[ty * 2 + 1];
    int n0 = qb + ty * 2;
#pragma unroll
    for (int j = 0; j < 4; ++j) {
      float4 o;
      o.x = acc0[j*4+0]*r0; o.y = acc0[j*4+1]*r0; o.z = acc0[j*4+2]*r0; o.w = acc0[j*4+3]*r0;
      *(float4*)&hp[(size_t)n0 * 1024 + hd * 256 + tx * 4 + 64 * j] = o;
      o.x = acc1[j*4+0]*r1; o.y = acc1[j*4+1]*r1; o.z = acc1[j*4+2]*r1; o.w = acc1[j*4+3]*r1;
      *(float4*)&hp[(size_t)(n0 + 1) * 1024 + hd * 256 + tx * 4 + 64 * j] = o;
    }
  }
}

// ---------------------------------------------------------------- misc small kernels
__global__ void k_zero(float* __restrict__ p, int n) {
  int i = blockIdx.x * blockDim.x + threadIdx.x;
  if (i < n) p[i] = 0.f;
}

__global__ __launch_bounds__(256) void k_segsum(const float* __restrict__ h,
                                                const int* __restrict__ lab,
                                                float* __restrict__ sums,
                                                float* __restrict__ cnt) {
  int i = blockIdx.x * blockDim.x + threadIdx.x;  // N*128
  int n = i >> 7, d = i & 127;
  int c = lab[n];
  atomicAdd(&sums[c * 128 + d], h[i]);
  if (d == 0) atomicAdd(&cnt[c], 1.0f);
}

__global__ __launch_bounds__(128) void k_gru(const float* __restrict__ sums,
                                             const float* __restrict__ cnt,
                                             const float* __restrict__ ch,
                                             const float* __restrict__ Wih,
                                             const float* __restrict__ bih,
                                             const float* __restrict__ Whh,
                                             const float* __restrict__ bhh,
                                             float* __restrict__ uch,
                                             float* __restrict__ out_uch) {
  int c = blockIdx.x, d = threadIdx.x;
  __shared__ float ax[128], hx[128];
  float count = cnt[c];
  ax[d] = sums[c * 128 + d] / fmaxf(count, 1.0f);
  hx[d] = ch[c * 128 + d];
  __syncthreads();
  float gi[3], gh[3];
#pragma unroll
  for (int g = 0; g < 3; ++g) {
    const float* wi = &Wih[(size_t)(g * 128 + d) * 128];
    const float* wh = &Whh[(size_t)(g * 128 + d) * 128];
    float si = 0.f, sh = 0.f;
#pragma unroll 4
    for (int e = 0; e < 128; ++e) {
      si = fmaf(ax[e], wi[e], si);
      sh = fmaf(hx[e], wh[e], sh);
    }
    gi[g] = si + bih[g * 128 + d];
    gh[g] = sh + bhh[g * 128 + d];
  }
  float r = 1.f / (1.f + expf(-(gi[0] + gh[0])));
  float z = 1.f / (1.f + expf(-(gi[1] + gh[1])));
  float nn = tanhf(gi[2] + r * gh[2]);
  float hv = hx[d];
  float nh = (1.f - z) * nn + z * hv;
  float res = (count > 0.f) ? nh : hv;
  uch[c * 128 + d] = res;
  out_uch[c * 128 + d] = res;
}

__global__ __launch_bounds__(128) void k_c2n(const float* __restrict__ uch,
                                             const float* __restrict__ Wp,
                                             const float* __restrict__ bp,
                                             float* __restrict__ c2n) {
  int c = blockIdx.x, d = threadIdx.x;
  __shared__ float u[128];
  u[d] = uch[c * 128 + d];
  __syncthreads();
  const float* w = &Wp[(size_t)d * 128];
  float s = 0.f;
#pragma unroll 4
  for (int e = 0; e < 128; ++e) s = fmaf(u[e], w[e], s);
  c2n[c * 128 + d] = s + bp[d];
}

__global__ __launch_bounds__(256) void k_final(const float* __restrict__ nr,
                                               const float* __restrict__ c2n,
                                               const int* __restrict__ lab,
                                               float* __restrict__ out) {
  int i = blockIdx.x * blockDim.x + threadIdx.x;  // N*128
  int n = i >> 7, d = i & 127;
  out[i] = nr[(size_t)n * 256 + 128 + d] + c2n[lab[n] * 128 + d];
}

// ---------------------------------------------------------------- launch
extern "C" void kernel_launch(void* const* d_in, const int* in_sizes, int n_in,
                              void* d_out, int out_size, void* d_ws, size_t ws_size,
                              hipStream_t stream) {
  const float* x    = (const float*)d_in[0];
  const float* h    = (const float*)d_in[1];
  const float* ch   = (const float*)d_in[2];
  const int*   lab  = (const int*)d_in[4];
  const float* Wq   = (const float*)d_in[8];
  const float* bq   = (const float*)d_in[9];
  const float* Wk   = (const float*)d_in[10];
  const float* bk   = (const float*)d_in[11];
  const float* Wv   = (const float*)d_in[12];
  const float* bv   = (const float*)d_in[13];
  const float* W1   = (const float*)d_in[14];
  const float* b1   = (const float*)d_in[15];
  const float* W2   = (const float*)d_in[16];
  const float* b2   = (const float*)d_in[17];
  const float* gWih = (const float*)d_in[18];
  const float* gbih = (const float*)d_in[19];
  const float* gWhh = (const float*)d_in[20];
  const float* gbhh = (const float*)d_in[21];
  const float* Wp   = (const float*)d_in[22];
  const float* bp   = (const float*)d_in[23];

  float* outp    = (float*)d_out;                 // [4096*128] updated_h
  float* out_uch = outp + 4096 * 128;             // [64*128] updated_cluster_h

  float* ws   = (float*)d_ws;
  float* comb = ws;                       // 4096*256   = 1,048,576
  float* qws  = comb + 4096 * 256;        // 4096*128   =   524,288
  float* kws  = qws + 4096 * 128;         // 4096*128   =   524,288
  float* vws  = kws + 4096 * 128;         // 4096*1024  = 4,194,304
  float* hp   = vws + 4096 * 1024;        // 4096*1024  = 4,194,304
  float* sums = hp + 4096 * 1024;         // 64*128
  float* cnt  = sums + 64 * 128;          // 64
  float* uch  = cnt + 64;                 // 64*128
  float* c2n  = uch + 64 * 128;           // 64*128
  float* y1   = vws;                      // alias: v dead after attention
  float* nr   = hp;                       // alias: hp dead after MLP1

  // combined = [x, h]
  k_combined<<<1024, 256, 0, stream>>>(x, h, comb);
  // Q, K, V projections (weights flatten to row-major [J][K])
  k_gemm<0><<<dim3(64, 2),  256, 0, stream>>>(comb, Wq, bq, nullptr, qws, 4096, 256, 128);
  k_gemm<0><<<dim3(64, 2),  256, 0, stream>>>(comb, Wk, bk, nullptr, kws, 4096, 256, 128);
  k_gemm<0><<<dim3(64, 16), 256, 0, stream>>>(comb, Wv, bv, nullptr, vws, 4096, 256, 1024);
  // flash attention -> hp [N][H*256]
  k_attn<<<dim3(128, 4), 256, 0, stream>>>(qws, kws, vws, hp);
  // MLP + residual
  k_gemm<1><<<dim3(64, 4), 256, 0, stream>>>(hp, W1, b1, nullptr, y1, 4096, 1024, 256);
  k_gemm<2><<<dim3(64, 4), 256, 0, stream>>>(y1, W2, b2, comb, nr, 4096, 256, 256);
  // cluster aggregation
  k_zero<<<33, 256, 0, stream>>>(sums, 64 * 128 + 64);
  k_segsum<<<2048, 256, 0, stream>>>(h, lab, sums, cnt);
  // GRU + masked update (also writes second output)
  k_gru<<<64, 128, 0, stream>>>(sums, cnt, ch, gWih, gbih, gWhh, gbhh, uch, out_uch);
  // cluster->node projection
  k_c2n<<<64, 128, 0, stream>>>(uch, Wp, bp, c2n);
  // final: node_repr[:, D:] + c2n[labels]
  k_final<<<2048, 256, 0, stream>>>(nr, c2n, lab, outp);
}

// Round 3
// 375.599 us; speedup vs baseline: 4.9839x; 4.9839x over previous
//
#include <hip/hip_runtime.h>
#include <math.h>

#define N_NODES 4096
#define NHEADS  4
#define NSPLIT  4
#define KVRANGE 1024   // 4096 / NSPLIT

typedef _Float16 f16;
typedef _Float16 half8 __attribute__((ext_vector_type(8)));
typedef float f32x4 __attribute__((ext_vector_type(4)));

// ---------------------------------------------------------------- combined
__global__ __launch_bounds__(256) void k_combined(const float* __restrict__ x,
                                                  const float* __restrict__ h,
                                                  float* __restrict__ comb) {
  int i = blockIdx.x * blockDim.x + threadIdx.x;   // over N*64 float4
  int n = i >> 6, c = i & 63;
  float4 v;
  if (c < 32) v = ((const float4*)x)[n * 32 + c];
  else        v = ((const float4*)h)[n * 32 + (c - 32)];
  ((float4*)comb)[i] = v;
}

// ---------------------------------------------------------------- GEMM
// out[m][j] = sum_k A[m][k] * W[j][k] + bias[j]   (+ epilogue)
// EPI: 0 none(f32), 1 relu(f32), 2 +resid(f32), 3 f16 out *alpha, 4 f16 transposed out
// ATRANS: A stored [K][M] (row stride M)
template <int EPI, bool ATRANS>
__global__ __launch_bounds__(256) void k_gemm(const float* __restrict__ A,
                                              const float* __restrict__ W,
                                              const float* __restrict__ bias,
                                              const float* __restrict__ resid,
                                              void* __restrict__ outv,
                                              int M, int K, int J, float alpha) {
  __shared__ float As[32][68];   // [k][m]
  __shared__ float Ws[32][68];   // [k][j]
  const int t  = threadIdx.x;
  const int mb = blockIdx.x * 64, jb = blockIdx.y * 64;
  const int tm = t & 15, tj = t >> 4;
  float acc[4][4] = {{0.f}};

  for (int kb = 0; kb < K; kb += 32) {
    __syncthreads();
    if (ATRANS) {
#pragma unroll
      for (int i = 0; i < 2; ++i) {
        int f = t + i * 256;                // 512 float4: 32 k-rows x 16 chunks
        int r = f >> 4, c4 = (f & 15) << 2;
        *(float4*)&As[r][c4] = *(const float4*)&A[(size_t)(kb + r) * M + mb + c4];
      }
    } else {
#pragma unroll
      for (int i = 0; i < 2; ++i) {
        int f  = t + i * 256;
        int r  = f >> 3;
        int c4 = (f & 7) << 2;
        float4 a = *(const float4*)&A[(size_t)(mb + r) * K + kb + c4];
        As[c4 + 0][r] = a.x; As[c4 + 1][r] = a.y;
        As[c4 + 2][r] = a.z; As[c4 + 3][r] = a.w;
      }
    }
#pragma unroll
    for (int i = 0; i < 2; ++i) {
      int f  = t + i * 256;
      int r  = f >> 3;
      int c4 = (f & 7) << 2;
      float4 w = *(const float4*)&W[(size_t)(jb + r) * K + kb + c4];
      Ws[c4 + 0][r] = w.x; Ws[c4 + 1][r] = w.y;
      Ws[c4 + 2][r] = w.z; Ws[c4 + 3][r] = w.w;
    }
    __syncthreads();
#pragma unroll
    for (int k = 0; k < 32; ++k) {
      float4 a = *(const float4*)&As[k][tm * 4];
      float4 b = *(const float4*)&Ws[k][tj * 4];
      float av[4] = {a.x, a.y, a.z, a.w};
      float bv[4] = {b.x, b.y, b.z, b.w};
#pragma unroll
      for (int i = 0; i < 4; ++i)
#pragma unroll
        for (int j = 0; j < 4; ++j)
          acc[i][j] = fmaf(av[i], bv[j], acc[i][j]);
    }
  }

  float bj[4];
#pragma unroll
  for (int j = 0; j < 4; ++j) bj[j] = bias[jb + tj * 4 + j];

  if (EPI <= 2) {
    float* out = (float*)outv;
#pragma unroll
    for (int i = 0; i < 4; ++i) {
      size_t m = mb + tm * 4 + i;
      float4 r;
      float* rr = (float*)&r;
#pragma unroll
      for (int j = 0; j < 4; ++j) {
        float v = acc[i][j] + bj[j];
        if (EPI == 1) v = fmaxf(v, 0.f);
        rr[j] = v;
      }
      if (EPI == 2) {
        float4 rs = *(const float4*)&resid[m * J + jb + tj * 4];
        r.x += rs.x; r.y += rs.y; r.z += rs.z; r.w += rs.w;
      }
      *(float4*)&out[m * J + jb + tj * 4] = r;
    }
  } else if (EPI == 3) {            // f16 regular layout, *alpha
    f16* out = (f16*)outv;
#pragma unroll
    for (int i = 0; i < 4; ++i) {
      size_t m = mb + tm * 4 + i;
      union { uint2 u; f16 h[4]; } pk_;
#pragma unroll
      for (int j = 0; j < 4; ++j) pk_.h[j] = (f16)((acc[i][j] + bj[j]) * alpha);
      *(uint2*)&out[m * J + jb + tj * 4] = pk_.u;
    }
  } else {                          // EPI 4: f16 transposed out[j][m]
    f16* out = (f16*)outv;
#pragma unroll
    for (int jj = 0; jj < 4; ++jj) {
      union { uint2 u; f16 h[4]; } pk_;
#pragma unroll
      for (int i = 0; i < 4; ++i) pk_.h[i] = (f16)(acc[i][jj] + bj[jj]);
      *(uint2*)&out[(size_t)(jb + tj * 4 + jj) * M + mb + tm * 4] = pk_.u;
    }
  }
}

// ---------------------------------------------------------------- MFMA flash attention
// qg,kg: f16 [N][128] (col = h*32+e, q pre-scaled by 1/sqrt(32))
// vt:    f16 [H*256][4096] (V transposed)
// Partials per kv-split: pO f16 [s][1024(j=h*256+d)][4096(q)] (normalized), pM/pL f32 [s][4][4096]
__global__ __launch_bounds__(256, 4) void k_attn_mfma(const f16* __restrict__ qg,
                                                      const f16* __restrict__ kg,
                                                      const f16* __restrict__ vt,
                                                      f16* __restrict__ pO,
                                                      float* __restrict__ pM,
                                                      float* __restrict__ pL) {
  const int hd  = blockIdx.y;
  const int sp  = blockIdx.z;
  const int kv0 = sp * KVRANGE;
  const int t   = threadIdx.x;
  const int w   = t >> 6, l = t & 63;
  const int g   = l >> 4, c = l & 15;
  const int qb  = blockIdx.x * 64 + w * 16;

  __shared__ f16 Ks[32 * 40];     // [kv_local][e], pad 40
  __shared__ f16 Vs[256 * 40];    // [d][kv_local], pad 40

  // Q fragment (B-operand): lane holds Q[qb+c][e = g*8 .. +7]
  half8 qf = *(const half8*)&qg[(size_t)(qb + c) * 128 + hd * 32 + g * 8];

  f32x4 oacc[16];
#pragma unroll
  for (int i = 0; i < 16; ++i) oacc[i] = (f32x4){0.f, 0.f, 0.f, 0.f};
  float m_run = -INFINITY, l_run = 0.f;

  // P-fragment remap constants (dest quarter g pulls from quarters 2g&3, (2g+1)&3)
  const int  srcA  = (((2 * g) & 3) << 4) + c;
  const int  srcB  = (((2 * g + 1) & 3) << 4) + c;
  const bool selhi = (g >> 1) != 0;
  const f32x4 zero4 = {0.f, 0.f, 0.f, 0.f};

  for (int kb = 0; kb < KVRANGE; kb += 32) {
    __syncthreads();
    if (t < 128) {        // K tile: 32 rows x 32 f16 = 128 uint4
      int r = t >> 2, c8 = (t & 3) * 8;
      *(uint4*)&Ks[r * 40 + c8] =
          *(const uint4*)&kg[(size_t)(kv0 + kb + r) * 128 + hd * 32 + c8];
    }
#pragma unroll
    for (int i = 0; i < 4; ++i) {  // V^T tile: 256 rows(d) x 32 f16(kv) = 1024 uint4
      int cc = i * 256 + t, d = cc >> 2, c8 = (cc & 3) * 8;
      *(uint4*)&Vs[d * 40 + c8] =
          *(const uint4*)&vt[(size_t)(hd * 256 + d) * 4096 + kv0 + kb + c8];
    }
    __syncthreads();

    // S^T = K . Q^T  (swapped): lane (g,c) reg r -> S[q=qb+c][kv = kb + g*4 + r] (s0), +16 (s1)
    f32x4 s0 = __builtin_amdgcn_mfma_f32_16x16x32_f16(
        *(const half8*)&Ks[(c) * 40 + g * 8], qf, zero4, 0, 0, 0);
    f32x4 s1 = __builtin_amdgcn_mfma_f32_16x16x32_f16(
        *(const half8*)&Ks[(16 + c) * 40 + g * 8], qf, zero4, 0, 0, 0);

    float sv[8];
#pragma unroll
    for (int r = 0; r < 4; ++r) {
      float a = s0[r]; sv[r]     = a > 0.f ? a : 0.2f * a;   // leaky(0.2), scale folded in q
      float b = s1[r]; sv[4 + r] = b > 0.f ? b : 0.2f * b;
    }
    // column max (per q = c) across 32 kv
    float mx = sv[0];
#pragma unroll
    for (int r = 1; r < 8; ++r) mx = fmaxf(mx, sv[r]);
    mx = fmaxf(mx, __shfl_xor(mx, 16));
    mx = fmaxf(mx, __shfl_xor(mx, 32));

    // defer-max: rescale only when some column grew by > 8
    if (!__all(mx <= m_run + 8.f)) {
      float m_new = fmaxf(m_run, mx);
      float cf = __expf(m_run - m_new);
#pragma unroll
      for (int i = 0; i < 16; ++i) {
        oacc[i][0] *= cf; oacc[i][1] *= cf; oacc[i][2] *= cf; oacc[i][3] *= cf;
      }
      l_run *= cf;
      m_run = m_new;
    }
    float p[8], ps = 0.f;
#pragma unroll
    for (int r = 0; r < 8; ++r) { p[r] = __expf(sv[r] - m_run); ps += p[r]; }
    ps += __shfl_xor(ps, 16);
    ps += __shfl_xor(ps, 32);
    l_run += ps;

    // pack P -> f16 pairs, remap to PV B-fragment layout (kv = g*8 + j)
    unsigned lo0, hi0, lo1, hi1;
    {
      union { unsigned u; f16 h[2]; } z;
      z.h[0] = (f16)p[0]; z.h[1] = (f16)p[1]; lo0 = z.u;
      z.h[0] = (f16)p[2]; z.h[1] = (f16)p[3]; hi0 = z.u;
      z.h[0] = (f16)p[4]; z.h[1] = (f16)p[5]; lo1 = z.u;
      z.h[0] = (f16)p[6]; z.h[1] = (f16)p[7]; hi1 = z.u;
    }
    int A0 = __shfl((int)lo0, srcA), A1 = __shfl((int)hi0, srcA);
    int A2 = __shfl((int)lo1, srcA), A3 = __shfl((int)hi1, srcA);
    int B0 = __shfl((int)lo0, srcB), B1 = __shfl((int)hi0, srcB);
    int B2 = __shfl((int)lo1, srcB), B3 = __shfl((int)hi1, srcB);
    union { half8 v; unsigned u[4]; } pf;
    pf.u[0] = (unsigned)(selhi ? A2 : A0);
    pf.u[1] = (unsigned)(selhi ? A3 : A1);
    pf.u[2] = (unsigned)(selhi ? B2 : B0);
    pf.u[3] = (unsigned)(selhi ? B3 : B1);

    // O^T += V^T . P^T : oacc[dt] covers d = dt*16 + g*4 + r, q = qb + c
#pragma unroll
    for (int dt = 0; dt < 16; ++dt)
      oacc[dt] = __builtin_amdgcn_mfma_f32_16x16x32_f16(
          *(const half8*)&Vs[(dt * 16 + c) * 40 + g * 8], pf.v, oacc[dt], 0, 0, 0);
  }

  // write normalized partial O^T (f16) + stats
  float inv = 1.f / l_run;
#pragma unroll
  for (int dt = 0; dt < 16; ++dt) {
#pragma unroll
    for (int r = 0; r < 4; ++r) {
      int j = hd * 256 + dt * 16 + g * 4 + r;
      pO[(size_t)(sp * 1024 + j) * 4096 + qb + c] = (f16)(oacc[dt][r] * inv);
    }
  }
  if (l < 16) {
    pM[(sp * 4 + hd) * 4096 + qb + l] = m_run;
    pL[(sp * 4 + hd) * 4096 + qb + l] = l_run;
  }
}

// ---------------------------------------------------------------- split-K merge -> hp^T f32 [1024][4096]
__global__ __launch_bounds__(256) void k_merge(const f16* __restrict__ pO,
                                               const float* __restrict__ pM,
                                               const float* __restrict__ pL,
                                               float* __restrict__ hp_t) {
  int i = blockIdx.x * 256 + threadIdx.x;   // 1024*4096
  int j = i >> 12, q = i & 4095, h = j >> 8;
  float m[NSPLIT], M = -INFINITY;
#pragma unroll
  for (int s = 0; s < NSPLIT; ++s) {
    m[s] = pM[(s * 4 + h) * 4096 + q];
    M = fmaxf(M, m[s]);
  }
  float L = 0.f, o = 0.f;
#pragma unroll
  for (int s = 0; s < NSPLIT; ++s) {
    float wgt = pL[(s * 4 + h) * 4096 + q] * __expf(m[s] - M);
    L += wgt;
    o += wgt * (float)pO[(size_t)(s * 1024 + j) * 4096 + q];
  }
  hp_t[(size_t)j * 4096 + q] = o / L;
}

// ---------------------------------------------------------------- misc small kernels
__global__ void k_zero(float* __restrict__ p, int n) {
  int i = blockIdx.x * blockDim.x + threadIdx.x;
  if (i < n) p[i] = 0.f;
}

__global__ __launch_bounds__(256) void k_segsum(const float* __restrict__ h,
                                                const int* __restrict__ lab,
                                                float* __restrict__ sums,
                                                float* __restrict__ cnt) {
  int i = blockIdx.x * blockDim.x + threadIdx.x;  // N*128
  int n = i >> 7, d = i & 127;
  int c = lab[n];
  atomicAdd(&sums[c * 128 + d], h[i]);
  if (d == 0) atomicAdd(&cnt[c], 1.0f);
}

__global__ __launch_bounds__(128) void k_gru(const float* __restrict__ sums,
                                             const float* __restrict__ cnt,
                                             const float* __restrict__ ch,
                                             const float* __restrict__ Wih,
                                             const float* __restrict__ bih,
                                             const float* __restrict__ Whh,
                                             const float* __restrict__ bhh,
                                             float* __restrict__ uch,
                                             float* __restrict__ out_uch) {
  int c = blockIdx.x, d = threadIdx.x;
  __shared__ float ax[128], hx[128];
  float count = cnt[c];
  ax[d] = sums[c * 128 + d] / fmaxf(count, 1.0f);
  hx[d] = ch[c * 128 + d];
  __syncthreads();
  float gi[3], gh[3];
#pragma unroll
  for (int g = 0; g < 3; ++g) {
    const float* wi = &Wih[(size_t)(g * 128 + d) * 128];
    const float* wh = &Whh[(size_t)(g * 128 + d) * 128];
    float si = 0.f, sh = 0.f;
#pragma unroll 4
    for (int e = 0; e < 128; ++e) {
      si = fmaf(ax[e], wi[e], si);
      sh = fmaf(hx[e], wh[e], sh);
    }
    gi[g] = si + bih[g * 128 + d];
    gh[g] = sh + bhh[g * 128 + d];
  }
  float r = 1.f / (1.f + expf(-(gi[0] + gh[0])));
  float z = 1.f / (1.f + expf(-(gi[1] + gh[1])));
  float nn = tanhf(gi[2] + r * gh[2]);
  float hv = hx[d];
  float nh = (1.f - z) * nn + z * hv;
  float res = (count > 0.f) ? nh : hv;
  uch[c * 128 + d] = res;
  out_uch[c * 128 + d] = res;
}

__global__ __launch_bounds__(128) void k_c2n(const float* __restrict__ uch,
                                             const float* __restrict__ Wp,
                                             const float* __restrict__ bp,
                                             float* __restrict__ c2n) {
  int c = blockIdx.x, d = threadIdx.x;
  __shared__ float u[128];
  u[d] = uch[c * 128 + d];
  __syncthreads();
  const float* w = &Wp[(size_t)d * 128];
  float s = 0.f;
#pragma unroll 4
  for (int e = 0; e < 128; ++e) s = fmaf(u[e], w[e], s);
  c2n[c * 128 + d] = s + bp[d];
}

__global__ __launch_bounds__(256) void k_final(const float* __restrict__ nr,
                                               const float* __restrict__ c2n,
                                               const int* __restrict__ lab,
                                               float* __restrict__ out) {
  int i = blockIdx.x * blockDim.x + threadIdx.x;  // N*128
  int n = i >> 7, d = i & 127;
  out[i] = nr[(size_t)n * 256 + 128 + d] + c2n[lab[n] * 128 + d];
}

// ---------------------------------------------------------------- launch
extern "C" void kernel_launch(void* const* d_in, const int* in_sizes, int n_in,
                              void* d_out, int out_size, void* d_ws, size_t ws_size,
                              hipStream_t stream) {
  const float* x    = (const float*)d_in[0];
  const float* h    = (const float*)d_in[1];
  const float* ch   = (const float*)d_in[2];
  const int*   lab  = (const int*)d_in[4];
  const float* Wq   = (const float*)d_in[8];
  const float* bq   = (const float*)d_in[9];
  const float* Wk   = (const float*)d_in[10];
  const float* bk   = (const float*)d_in[11];
  const float* Wv   = (const float*)d_in[12];
  const float* bv   = (const float*)d_in[13];
  const float* W1   = (const float*)d_in[14];
  const float* b1   = (const float*)d_in[15];
  const float* W2   = (const float*)d_in[16];
  const float* b2   = (const float*)d_in[17];
  const float* gWih = (const float*)d_in[18];
  const float* gbih = (const float*)d_in[19];
  const float* gWhh = (const float*)d_in[20];
  const float* gbhh = (const float*)d_in[21];
  const float* Wp   = (const float*)d_in[22];
  const float* bp   = (const float*)d_in[23];

  float* outp    = (float*)d_out;                 // [4096*128] updated_h
  float* out_uch = outp + 4096 * 128;             // [64*128] updated_cluster_h

  // workspace layout (f32 slots)
  float* ws    = (float*)d_ws;
  float* comb  = ws;                               // 1,048,576
  float* hp_t  = comb + 1048576;                   // 4,194,304  f32 [1024][4096]
  f16*   qf16  = (f16*)(hp_t + 4194304);           // 524,288 halfs
  f16*   kf16  = qf16 + 524288;                    // 524,288 halfs
  f16*   vt16  = kf16 + 524288;                    // 4,194,304 halfs [1024][4096]
  f16*   pO    = vt16 + 4194304;                   // NSPLIT*1024*4096 halfs
  float* pM    = (float*)(pO + (size_t)NSPLIT * 1024 * 4096);  // NSPLIT*4*4096
  float* pL    = pM + NSPLIT * 4 * 4096;
  float* sums  = pL + NSPLIT * 4 * 4096;           // 8192
  float* cnt   = sums + 64 * 128;                  // 64
  float* uch   = cnt + 64;                         // 8192
  float* c2n   = uch + 64 * 128;                   // 8192
  // y1 / nr aliased over pO (dead after k_merge)
  float* y1    = (float*)pO;                       // 1,048,576
  float* nr    = y1 + 1048576;                     // 1,048,576

  const float qscale = 0.17677669529663687f;       // 1/sqrt(32)

  // combined = [x, h]
  k_combined<<<1024, 256, 0, stream>>>(x, h, comb);
  // projections: Q (f16, pre-scaled), K (f16), V (f16, transposed)
  k_gemm<3, false><<<dim3(64, 2),  256, 0, stream>>>(comb, Wq, bq, nullptr, qf16, 4096, 256, 128,  qscale);
  k_gemm<3, false><<<dim3(64, 2),  256, 0, stream>>>(comb, Wk, bk, nullptr, kf16, 4096, 256, 128,  1.0f);
  k_gemm<4, false><<<dim3(64, 16), 256, 0, stream>>>(comb, Wv, bv, nullptr, vt16, 4096, 256, 1024, 1.0f);
  // MFMA flash attention (split-K) + merge -> hp^T
  k_attn_mfma<<<dim3(64, NHEADS, NSPLIT), 256, 0, stream>>>(qf16, kf16, vt16, pO, pM, pL);
  k_merge<<<16384, 256, 0, stream>>>(pO, pM, pL, hp_t);
  // MLP (A transposed) + residual
  k_gemm<1, true ><<<dim3(64, 4), 256, 0, stream>>>(hp_t, W1, b1, nullptr, y1, 4096, 1024, 256, 1.0f);
  k_gemm<2, false><<<dim3(64, 4), 256, 0, stream>>>(y1,   W2, b2, comb,    nr, 4096, 256,  256, 1.0f);
  // cluster aggregation
  k_zero<<<33, 256, 0, stream>>>(sums, 64 * 128 + 64);
  k_segsum<<<2048, 256, 0, stream>>>(h, lab, sums, cnt);
  // GRU + masked update (also writes second output)
  k_gru<<<64, 128, 0, stream>>>(sums, cnt, ch, gWih, gbih, gWhh, gbhh, uch, out_uch);
  // cluster->node projection
  k_c2n<<<64, 128, 0, stream>>>(uch, Wp, bp, c2n);
  // final: node_repr[:, D:] + c2n[labels]
  k_final<<<2048, 256, 0, stream>>>(nr, c2n, lab, outp);
}

// Round 4
// 287.750 us; speedup vs baseline: 6.5055x; 1.3053x over previous
//
#include <hip/hip_runtime.h>
#include <math.h>

#define N_NODES 4096
#define NHEADS  4
#define NSPLIT  4
#define KVRANGE 1024   // 4096 / NSPLIT

typedef _Float16 f16;
typedef _Float16 half8 __attribute__((ext_vector_type(8)));
typedef float f32x4 __attribute__((ext_vector_type(4)));

// ---------------------------------------------------------------- combined (f16)
__global__ __launch_bounds__(256) void k_combined(const float* __restrict__ x,
                                                  const float* __restrict__ h,
                                                  f16* __restrict__ comb16) {
  int i = blockIdx.x * blockDim.x + threadIdx.x;   // over N*64 float4
  int n = i >> 6, c = i & 63;
  float4 v;
  if (c < 32) v = ((const float4*)x)[n * 32 + c];
  else        v = ((const float4*)h)[n * 32 + (c - 32)];
  union { uint2 u; f16 h4[4]; } pk;
  pk.h4[0] = (f16)v.x; pk.h4[1] = (f16)v.y; pk.h4[2] = (f16)v.z; pk.h4[3] = (f16)v.w;
  *(uint2*)&comb16[(size_t)i * 4] = pk.u;
}

// ---------------------------------------------------------------- weights -> f16
// pool: [Wq 32768][Wk 32768][Wv 262144][W1 262144][W2 65536] = 655360
__global__ __launch_bounds__(256) void k_w2h(const float* __restrict__ Wq,
                                             const float* __restrict__ Wk,
                                             const float* __restrict__ Wv,
                                             const float* __restrict__ W1,
                                             const float* __restrict__ W2,
                                             f16* __restrict__ pool) {
  int i4 = (blockIdx.x * 256 + threadIdx.x) * 4;   // 655360 total, grid 640
  const float* src; int off;
  if      (i4 <  32768) { src = Wq; off = 0; }
  else if (i4 <  65536) { src = Wk; off = 32768; }
  else if (i4 < 327680) { src = Wv; off = 65536; }
  else if (i4 < 589824) { src = W1; off = 327680; }
  else                  { src = W2; off = 589824; }
  float4 v = *(const float4*)&src[i4 - off];
  union { uint2 u; f16 h4[4]; } pk;
  pk.h4[0] = (f16)v.x; pk.h4[1] = (f16)v.y; pk.h4[2] = (f16)v.z; pk.h4[3] = (f16)v.w;
  *(uint2*)&pool[i4] = pk.u;
}

// ---------------------------------------------------------------- MFMA GEMM (f16 in, f32 acc)
// out[m][j] = sum_k A[m][k] * B[j][k] (+ bias) ; A [M][K], B [J][K] f16, K % 64 == 0
// EPI: 0 f16 out, col-bias, *alpha   1 f16 out, col-bias, relu
//      2 f16 out, row-bias           3 f32 out, col-bias, + resid[m*J+j]
template <int EPI>
__global__ __launch_bounds__(256) void k_gemm16(const f16* __restrict__ A,
                                                const f16* __restrict__ B,
                                                const float* __restrict__ bias,
                                                const float* __restrict__ resid,
                                                void* __restrict__ outv,
                                                int M, int K, int J, float alpha) {
  __shared__ f16 As[64 * 64];   // 64 rows x 128B, XOR-swizzled chunks
  __shared__ f16 Bs[64 * 64];
  const int t  = threadIdx.x;
  const int mb = blockIdx.x * 64, jb = blockIdx.y * 64;
  const int w  = t >> 6, l = t & 63;
  const int g_ = l >> 4, c_ = l & 15;
  const int m0 = (w >> 1) * 32, n0 = (w & 1) * 32;

  f32x4 acc[2][2];
#pragma unroll
  for (int i = 0; i < 2; ++i)
#pragma unroll
    for (int j = 0; j < 2; ++j) acc[i][j] = (f32x4){0.f, 0.f, 0.f, 0.f};

#define FRAG16(BUF, row, kh) \
  (*(const half8*)&BUF[(size_t)(row) * 64 + (((((kh) * 4 + g_) ^ (c_ & 7))) << 3)])

  for (int kb = 0; kb < K; kb += 64) {
    __syncthreads();
#pragma unroll
    for (int i = 0; i < 2; ++i) {
      int f = t + i * 256;            // 512 uint4 per matrix tile
      int r = f >> 3, ch = f & 7;
      *(uint4*)&As[r * 64 + ((ch ^ (r & 7)) << 3)] =
          *(const uint4*)&A[(size_t)(mb + r) * K + kb + ch * 8];
      *(uint4*)&Bs[r * 64 + ((ch ^ (r & 7)) << 3)] =
          *(const uint4*)&B[(size_t)(jb + r) * K + kb + ch * 8];
    }
    __syncthreads();
#pragma unroll
    for (int kh = 0; kh < 2; ++kh) {
      half8 a0 = FRAG16(As, m0 + c_, kh);
      half8 a1 = FRAG16(As, m0 + 16 + c_, kh);
      half8 b0 = FRAG16(Bs, n0 + c_, kh);
      half8 b1 = FRAG16(Bs, n0 + 16 + c_, kh);
      acc[0][0] = __builtin_amdgcn_mfma_f32_16x16x32_f16(a0, b0, acc[0][0], 0, 0, 0);
      acc[0][1] = __builtin_amdgcn_mfma_f32_16x16x32_f16(a0, b1, acc[0][1], 0, 0, 0);
      acc[1][0] = __builtin_amdgcn_mfma_f32_16x16x32_f16(a1, b0, acc[1][0], 0, 0, 0);
      acc[1][1] = __builtin_amdgcn_mfma_f32_16x16x32_f16(a1, b1, acc[1][1], 0, 0, 0);
    }
  }
#undef FRAG16

#pragma unroll
  for (int mt = 0; mt < 2; ++mt)
#pragma unroll
    for (int nt = 0; nt < 2; ++nt) {
      int mbase = mb + m0 + mt * 16 + g_ * 4;
      int jj    = jb + n0 + nt * 16 + c_;
      if (EPI == 0 || EPI == 1) {
        f16* out = (f16*)outv;
        float bc = bias[jj];
#pragma unroll
        for (int r = 0; r < 4; ++r) {
          float v = (acc[mt][nt][r] + bc) * alpha;
          if (EPI == 1) v = fmaxf(v, 0.f);
          out[(size_t)(mbase + r) * J + jj] = (f16)v;
        }
      } else if (EPI == 2) {
        f16* out = (f16*)outv;
#pragma unroll
        for (int r = 0; r < 4; ++r)
          out[(size_t)(mbase + r) * J + jj] = (f16)(acc[mt][nt][r] + bias[mbase + r]);
      } else {
        float* out = (float*)outv;
        float bc = bias[jj];
#pragma unroll
        for (int r = 0; r < 4; ++r)
          out[(size_t)(mbase + r) * J + jj] =
              acc[mt][nt][r] + bc + resid[(size_t)(mbase + r) * J + jj];
      }
    }
}

// ---------------------------------------------------------------- MFMA flash attention
// qg,kg: f16 [N][128] (col = h*32+e, q pre-scaled by 1/sqrt(32))
// vt:    f16 [H*256][4096] (V transposed)
// Partials per kv-split: pO f16 [s][1024(j=h*256+d)][4096(q)] (normalized), pM/pL f32 [s][4][4096]
__global__ __launch_bounds__(256, 4) void k_attn_mfma(const f16* __restrict__ qg,
                                                      const f16* __restrict__ kg,
                                                      const f16* __restrict__ vt,
                                                      f16* __restrict__ pO,
                                                      float* __restrict__ pM,
                                                      float* __restrict__ pL) {
  const int hd  = blockIdx.y;
  const int sp  = blockIdx.z;
  const int kv0 = sp * KVRANGE;
  const int t   = threadIdx.x;
  const int w   = t >> 6, l = t & 63;
  const int g   = l >> 4, c = l & 15;
  const int qb  = blockIdx.x * 64 + w * 16;

  __shared__ f16 Ks[32 * 40];     // [kv_local][e], pad 40
  __shared__ f16 Vs[256 * 40];    // [d][kv_local], pad 40

  // Q fragment (B-operand): lane holds Q[qb+c][e = g*8 .. +7]
  half8 qf = *(const half8*)&qg[(size_t)(qb + c) * 128 + hd * 32 + g * 8];

  f32x4 oacc[16];
#pragma unroll
  for (int i = 0; i < 16; ++i) oacc[i] = (f32x4){0.f, 0.f, 0.f, 0.f};
  float m_run = -INFINITY, l_run = 0.f;

  const int  srcA  = (((2 * g) & 3) << 4) + c;
  const int  srcB  = (((2 * g + 1) & 3) << 4) + c;
  const bool selhi = (g >> 1) != 0;
  const f32x4 zero4 = {0.f, 0.f, 0.f, 0.f};

  for (int kb = 0; kb < KVRANGE; kb += 32) {
    __syncthreads();
    if (t < 128) {        // K tile: 32 rows x 32 f16 = 128 uint4
      int r = t >> 2, c8 = (t & 3) * 8;
      *(uint4*)&Ks[r * 40 + c8] =
          *(const uint4*)&kg[(size_t)(kv0 + kb + r) * 128 + hd * 32 + c8];
    }
#pragma unroll
    for (int i = 0; i < 4; ++i) {  // V^T tile: 256 rows(d) x 32 f16(kv) = 1024 uint4
      int cc = i * 256 + t, d = cc >> 2, c8 = (cc & 3) * 8;
      *(uint4*)&Vs[d * 40 + c8] =
          *(const uint4*)&vt[(size_t)(hd * 256 + d) * 4096 + kv0 + kb + c8];
    }
    __syncthreads();

    // S^T = K . Q^T (swapped): lane (g,c) reg r -> S[q=qb+c][kv = kb + g*4 + r] (s0), +16 (s1)
    f32x4 s0 = __builtin_amdgcn_mfma_f32_16x16x32_f16(
        *(const half8*)&Ks[(c) * 40 + g * 8], qf, zero4, 0, 0, 0);
    f32x4 s1 = __builtin_amdgcn_mfma_f32_16x16x32_f16(
        *(const half8*)&Ks[(16 + c) * 40 + g * 8], qf, zero4, 0, 0, 0);

    float sv[8];
#pragma unroll
    for (int r = 0; r < 4; ++r) {
      float a = s0[r]; sv[r]     = a > 0.f ? a : 0.2f * a;   // leaky(0.2), scale folded in q
      float b = s1[r]; sv[4 + r] = b > 0.f ? b : 0.2f * b;
    }
    float mx = sv[0];
#pragma unroll
    for (int r = 1; r < 8; ++r) mx = fmaxf(mx, sv[r]);
    mx = fmaxf(mx, __shfl_xor(mx, 16));
    mx = fmaxf(mx, __shfl_xor(mx, 32));

    // defer-max: rescale only when some column grew by > 8
    if (!__all(mx <= m_run + 8.f)) {
      float m_new = fmaxf(m_run, mx);
      float cf = __expf(m_run - m_new);
#pragma unroll
      for (int i = 0; i < 16; ++i) {
        oacc[i][0] *= cf; oacc[i][1] *= cf; oacc[i][2] *= cf; oacc[i][3] *= cf;
      }
      l_run *= cf;
      m_run = m_new;
    }
    float p[8], ps = 0.f;
#pragma unroll
    for (int r = 0; r < 8; ++r) { p[r] = __expf(sv[r] - m_run); ps += p[r]; }
    ps += __shfl_xor(ps, 16);
    ps += __shfl_xor(ps, 32);
    l_run += ps;

    // pack P -> f16 pairs, remap to PV B-fragment layout (kv = g*8 + j)
    unsigned lo0, hi0, lo1, hi1;
    {
      union { unsigned u; f16 h[2]; } z;
      z.h[0] = (f16)p[0]; z.h[1] = (f16)p[1]; lo0 = z.u;
      z.h[0] = (f16)p[2]; z.h[1] = (f16)p[3]; hi0 = z.u;
      z.h[0] = (f16)p[4]; z.h[1] = (f16)p[5]; lo1 = z.u;
      z.h[0] = (f16)p[6]; z.h[1] = (f16)p[7]; hi1 = z.u;
    }
    int A0 = __shfl((int)lo0, srcA), A1 = __shfl((int)hi0, srcA);
    int A2 = __shfl((int)lo1, srcA), A3 = __shfl((int)hi1, srcA);
    int B0 = __shfl((int)lo0, srcB), B1 = __shfl((int)hi0, srcB);
    int B2 = __shfl((int)lo1, srcB), B3 = __shfl((int)hi1, srcB);
    union { half8 v; unsigned u[4]; } pf;
    pf.u[0] = (unsigned)(selhi ? A2 : A0);
    pf.u[1] = (unsigned)(selhi ? A3 : A1);
    pf.u[2] = (unsigned)(selhi ? B2 : B0);
    pf.u[3] = (unsigned)(selhi ? B3 : B1);

    // O^T += V^T . P^T
#pragma unroll
    for (int dt = 0; dt < 16; ++dt)
      oacc[dt] = __builtin_amdgcn_mfma_f32_16x16x32_f16(
          *(const half8*)&Vs[(dt * 16 + c) * 40 + g * 8], pf.v, oacc[dt], 0, 0, 0);
  }

  float inv = 1.f / l_run;
#pragma unroll
  for (int dt = 0; dt < 16; ++dt) {
#pragma unroll
    for (int r = 0; r < 4; ++r) {
      int j = hd * 256 + dt * 16 + g * 4 + r;
      pO[(size_t)(sp * 1024 + j) * 4096 + qb + c] = (f16)(oacc[dt][r] * inv);
    }
  }
  if (l < 16) {
    pM[(sp * 4 + hd) * 4096 + qb + l] = m_run;
    pL[(sp * 4 + hd) * 4096 + qb + l] = l_run;
  }
}

// ---------------------------------------------------------------- split-K merge -> hp16 [4096][1024]
__global__ __launch_bounds__(256) void k_merge(const f16* __restrict__ pO,
                                               const float* __restrict__ pM,
                                               const float* __restrict__ pL,
                                               f16* __restrict__ hp) {
  const int q0 = blockIdx.x * 64, jb = blockIdx.y * 64;
  const int h  = jb >> 8;
  const int t  = threadIdx.x;
  __shared__ float wm[NSPLIT][64], wl[NSPLIT][64];
  __shared__ float tile[64][65];

  if (t < 64) {
#pragma unroll
    for (int s = 0; s < NSPLIT; ++s) {
      wm[s][t] = pM[(s * 4 + h) * 4096 + q0 + t];
      wl[s][t] = pL[(s * 4 + h) * 4096 + q0 + t];
    }
  }
  __syncthreads();

  const int q8 = (t & 7) * 8;
#pragma unroll
  for (int it = 0; it < 2; ++it) {
    int jl = (t >> 3) + it * 32;
    float wgt[NSPLIT][8], inv[8];
#pragma unroll
    for (int q = 0; q < 8; ++q) {
      float M = wm[0][q8 + q];
#pragma unroll
      for (int s = 1; s < NSPLIT; ++s) M = fmaxf(M, wm[s][q8 + q]);
      float den = 0.f;
#pragma unroll
      for (int s = 0; s < NSPLIT; ++s) {
        float wv = wl[s][q8 + q] * __expf(wm[s][q8 + q] - M);
        wgt[s][q] = wv; den += wv;
      }
      inv[q] = 1.f / den;
    }
    float o[8] = {0.f};
#pragma unroll
    for (int s = 0; s < NSPLIT; ++s) {
      union { uint4 u; f16 h8[8]; } raw;
      raw.u = *(const uint4*)&pO[(size_t)(s * 1024 + jb + jl) * 4096 + q0 + q8];
#pragma unroll
      for (int q = 0; q < 8; ++q) o[q] += wgt[s][q] * (float)raw.h8[q];
    }
#pragma unroll
    for (int q = 0; q < 8; ++q) tile[q8 + q][jl] = o[q] * inv[q];
  }
  __syncthreads();

#pragma unroll
  for (int it = 0; it < 2; ++it) {
    int ql = (t >> 3) + it * 32, chk = t & 7;
    union { uint4 u; f16 h8[8]; } pk;
#pragma unroll
    for (int k = 0; k < 8; ++k) pk.h8[k] = (f16)tile[ql][chk * 8 + k];
    *(uint4*)&hp[(size_t)(q0 + ql) * 1024 + jb + chk * 8] = pk.u;
  }
}

// ---------------------------------------------------------------- misc small kernels
__global__ void k_zero(float* __restrict__ p, int n) {
  int i = blockIdx.x * blockDim.x + threadIdx.x;
  if (i < n) p[i] = 0.f;
}

__global__ __launch_bounds__(256) void k_segsum(const float* __restrict__ h,
                                                const int* __restrict__ lab,
                                                float* __restrict__ sums,
                                                float* __restrict__ cnt) {
  int i = blockIdx.x * blockDim.x + threadIdx.x;  // N*128
  int n = i >> 7, d = i & 127;
  int c = lab[n];
  atomicAdd(&sums[c * 128 + d], h[i]);
  if (d == 0) atomicAdd(&cnt[c], 1.0f);
}

__global__ __launch_bounds__(128) void k_gru(const float* __restrict__ sums,
                                             const float* __restrict__ cnt,
                                             const float* __restrict__ ch,
                                             const float* __restrict__ Wih,
                                             const float* __restrict__ bih,
                                             const float* __restrict__ Whh,
                                             const float* __restrict__ bhh,
                                             float* __restrict__ uch,
                                             float* __restrict__ out_uch) {
  int c = blockIdx.x, d = threadIdx.x;
  __shared__ float ax[128], hx[128];
  float count = cnt[c];
  ax[d] = sums[c * 128 + d] / fmaxf(count, 1.0f);
  hx[d] = ch[c * 128 + d];
  __syncthreads();
  float gi[3], gh[3];
#pragma unroll
  for (int g = 0; g < 3; ++g) {
    const float* wi = &Wih[(size_t)(g * 128 + d) * 128];
    const float* wh = &Whh[(size_t)(g * 128 + d) * 128];
    float si = 0.f, sh = 0.f;
#pragma unroll 4
    for (int e = 0; e < 128; ++e) {
      si = fmaf(ax[e], wi[e], si);
      sh = fmaf(hx[e], wh[e], sh);
    }
    gi[g] = si + bih[g * 128 + d];
    gh[g] = sh + bhh[g * 128 + d];
  }
  float r = 1.f / (1.f + expf(-(gi[0] + gh[0])));
  float z = 1.f / (1.f + expf(-(gi[1] + gh[1])));
  float nn = tanhf(gi[2] + r * gh[2]);
  float hv = hx[d];
  float nh = (1.f - z) * nn + z * hv;
  float res = (count > 0.f) ? nh : hv;
  uch[c * 128 + d] = res;
  out_uch[c * 128 + d] = res;
}

__global__ __launch_bounds__(128) void k_c2n(const float* __restrict__ uch,
                                             const float* __restrict__ Wp,
                                             const float* __restrict__ bp,
                                             float* __restrict__ c2n) {
  int c = blockIdx.x, d = threadIdx.x;
  __shared__ float u[128];
  u[d] = uch[c * 128 + d];
  __syncthreads();
  const float* w = &Wp[(size_t)d * 128];
  float s = 0.f;
#pragma unroll 4
  for (int e = 0; e < 128; ++e) s = fmaf(u[e], w[e], s);
  c2n[c * 128 + d] = s + bp[d];
}

// final: out = nr_half[n][d] + c2n[lab[n]][d]   (nr_half is MLP2 cols 128..255 + h resid)
__global__ __launch_bounds__(256) void k_final(const float* __restrict__ nrh,
                                               const float* __restrict__ c2n,
                                               const int* __restrict__ lab,
                                               float* __restrict__ out) {
  int i = blockIdx.x * blockDim.x + threadIdx.x;  // N*128
  int n = i >> 7, d = i & 127;
  out[i] = nrh[(size_t)n * 128 + d] + c2n[lab[n] * 128 + d];
}

// ---------------------------------------------------------------- launch
extern "C" void kernel_launch(void* const* d_in, const int* in_sizes, int n_in,
                              void* d_out, int out_size, void* d_ws, size_t ws_size,
                              hipStream_t stream) {
  const float* x    = (const float*)d_in[0];
  const float* h    = (const float*)d_in[1];
  const float* ch   = (const float*)d_in[2];
  const int*   lab  = (const int*)d_in[4];
  const float* Wq   = (const float*)d_in[8];
  const float* bq   = (const float*)d_in[9];
  const float* Wk   = (const float*)d_in[10];
  const float* bk   = (const float*)d_in[11];
  const float* Wv   = (const float*)d_in[12];
  const float* bv   = (const float*)d_in[13];
  const float* W1   = (const float*)d_in[14];
  const float* b1   = (const float*)d_in[15];
  const float* W2   = (const float*)d_in[16];
  const float* b2   = (const float*)d_in[17];
  const float* gWih = (const float*)d_in[18];
  const float* gbih = (const float*)d_in[19];
  const float* gWhh = (const float*)d_in[20];
  const float* gbhh = (const float*)d_in[21];
  const float* Wp   = (const float*)d_in[22];
  const float* bp   = (const float*)d_in[23];

  float* outp    = (float*)d_out;                 // [4096*128] updated_h
  float* out_uch = outp + 4096 * 128;             // [64*128] updated_cluster_h

  // ---- workspace layout
  f16* comb16 = (f16*)d_ws;                        // 4096*256
  f16* w16    = comb16 + 4096 * 256;               // 655360
  f16* wq16   = w16;                               //  32768
  f16* wk16   = w16 + 32768;
  f16* wv16   = w16 + 65536;                       // 262144 [1024][256]
  f16* w116   = w16 + 327680;                      // 262144 [256][1024]
  f16* w216   = w16 + 589824;                      //  65536 [256][256]
  f16* qf16   = w16 + 655360;                      // 4096*128
  f16* kf16   = qf16 + 4096 * 128;                 // 4096*128
  f16* vt16   = kf16 + 4096 * 128;                 // 1024*4096
  f16* pO     = vt16 + 1024 * 4096;                // 4*1024*4096
  f16* hp16   = pO + (size_t)NSPLIT * 1024 * 4096; // 4096*1024
  f16* y116   = hp16 + (size_t)4096 * 1024;        // 4096*256
  float* pM   = (float*)(y116 + 4096 * 256);       // 4*4*4096
  float* pL   = pM + NSPLIT * 4 * 4096;
  float* nrh  = pL + NSPLIT * 4 * 4096;            // 4096*128 f32
  float* sums = nrh + 4096 * 128;                  // 8192
  float* cnt  = sums + 64 * 128;                   // 64
  float* uch  = cnt + 64;                          // 8192
  float* c2n  = uch + 64 * 128;                    // 8192

  const float qscale = 0.17677669529663687f;       // 1/sqrt(32)

  // combined (f16) + weight conversion
  k_combined<<<1024, 256, 0, stream>>>(x, h, comb16);
  k_w2h<<<640, 256, 0, stream>>>(Wq, Wk, Wv, W1, W2, w16);
  // projections (MFMA): Q (scaled), K, V^T (swapped operands, row-bias)
  k_gemm16<0><<<dim3(64, 2),  256, 0, stream>>>(comb16, wq16, bq, nullptr, qf16, 4096, 256, 128,  qscale);
  k_gemm16<0><<<dim3(64, 2),  256, 0, stream>>>(comb16, wk16, bk, nullptr, kf16, 4096, 256, 128,  1.0f);
  k_gemm16<2><<<dim3(16, 64), 256, 0, stream>>>(wv16, comb16, bv, nullptr, vt16, 1024, 256, 4096, 1.0f);
  // flash attention (split-K) + merge -> hp16 [4096][1024]
  k_attn_mfma<<<dim3(64, NHEADS, NSPLIT), 256, 0, stream>>>(qf16, kf16, vt16, pO, pM, pL);
  k_merge<<<dim3(64, 16), 256, 0, stream>>>(pO, pM, pL, hp16);
  // MLP: y1 = relu(hp @ W1^T + b1); nr_half = (y1 @ W2[128:]^T + b2[128:]) + h
  k_gemm16<1><<<dim3(64, 4), 256, 0, stream>>>(hp16, w116, b1, nullptr, y116, 4096, 1024, 256, 1.0f);
  k_gemm16<3><<<dim3(64, 2), 256, 0, stream>>>(y116, w216 + 128 * 256, b2 + 128, h, nrh, 4096, 256, 128, 1.0f);
  // cluster aggregation
  k_zero<<<33, 256, 0, stream>>>(sums, 64 * 128 + 64);
  k_segsum<<<2048, 256, 0, stream>>>(h, lab, sums, cnt);
  // GRU + masked update (also writes second output)
  k_gru<<<64, 128, 0, stream>>>(sums, cnt, ch, gWih, gbih, gWhh, gbhh, uch, out_uch);
  // cluster->node projection
  k_c2n<<<64, 128, 0, stream>>>(uch, Wp, bp, c2n);
  // final
  k_final<<<2048, 256, 0, stream>>>(nrh, c2n, lab, outp);
}

// Round 6
// 270.837 us; speedup vs baseline: 6.9117x; 1.0624x over previous
//
#include <hip/hip_runtime.h>
#include <math.h>

#define N_NODES 4096
#define NHEADS  4
#define NSPLIT  4
#define KVRANGE 1024   // 4096 / NSPLIT

typedef _Float16 f16;
typedef _Float16 half8 __attribute__((ext_vector_type(8)));
typedef float f32x4 __attribute__((ext_vector_type(4)));

// ---------------------------------------------------------------- combined (f16)
__global__ __launch_bounds__(256) void k_combined(const float* __restrict__ x,
                                                  const float* __restrict__ h,
                                                  f16* __restrict__ comb16) {
  int i = blockIdx.x * blockDim.x + threadIdx.x;   // over N*64 float4
  int n = i >> 6, c = i & 63;
  float4 v;
  if (c < 32) v = ((const float4*)x)[n * 32 + c];
  else        v = ((const float4*)h)[n * 32 + (c - 32)];
  union { uint2 u; f16 h4[4]; } pk;
  pk.h4[0] = (f16)v.x; pk.h4[1] = (f16)v.y; pk.h4[2] = (f16)v.z; pk.h4[3] = (f16)v.w;
  *(uint2*)&comb16[(size_t)i * 4] = pk.u;
}

// ---------------------------------------------------------------- weights -> f16
// pool: [Wq 32768][Wk 32768][Wv 262144][W1 262144][W2 65536] = 655360
__global__ __launch_bounds__(256) void k_w2h(const float* __restrict__ Wq,
                                             const float* __restrict__ Wk,
                                             const float* __restrict__ Wv,
                                             const float* __restrict__ W1,
                                             const float* __restrict__ W2,
                                             f16* __restrict__ pool) {
  int i4 = (blockIdx.x * 256 + threadIdx.x) * 4;   // 655360 total, grid 640
  const float* src; int off;
  if      (i4 <  32768) { src = Wq; off = 0; }
  else if (i4 <  65536) { src = Wk; off = 32768; }
  else if (i4 < 327680) { src = Wv; off = 65536; }
  else if (i4 < 589824) { src = W1; off = 327680; }
  else                  { src = W2; off = 589824; }
  float4 v = *(const float4*)&src[i4 - off];
  union { uint2 u; f16 h4[4]; } pk;
  pk.h4[0] = (f16)v.x; pk.h4[1] = (f16)v.y; pk.h4[2] = (f16)v.z; pk.h4[3] = (f16)v.w;
  *(uint2*)&pool[i4] = pk.u;
}

// ---------------------------------------------------------------- MFMA GEMM (f16 in, f32 acc)
// out[m][j] = sum_k A[m][k] * B[j][k] (+ bias) ; A [M][K], B [J][K] f16, K % 64 == 0
// EPI: 0 f16 out, col-bias, *alpha   1 f16 out, col-bias, relu
//      2 f16 out, row-bias           3 f32 out, col-bias, + resid + c2n[lab[m]]
template <int EPI>
__global__ __launch_bounds__(256) void k_gemm16(const f16* __restrict__ A,
                                                const f16* __restrict__ B,
                                                const float* __restrict__ bias,
                                                const float* __restrict__ resid,
                                                const int* __restrict__ lab,
                                                const float* __restrict__ c2n,
                                                void* __restrict__ outv,
                                                int M, int K, int J, float alpha) {
  __shared__ f16 As[64 * 64];   // 64 rows x 128B, XOR-swizzled chunks
  __shared__ f16 Bs[64 * 64];
  const int t  = threadIdx.x;
  const int mb = blockIdx.x * 64, jb = blockIdx.y * 64;
  const int w  = t >> 6, l = t & 63;
  const int g_ = l >> 4, c_ = l & 15;
  const int m0 = (w >> 1) * 32, n0 = (w & 1) * 32;

  f32x4 acc[2][2];
#pragma unroll
  for (int i = 0; i < 2; ++i)
#pragma unroll
    for (int j = 0; j < 2; ++j) acc[i][j] = (f32x4){0.f, 0.f, 0.f, 0.f};

#define FRAG16(BUF, row, kh) \
  (*(const half8*)&BUF[(size_t)(row) * 64 + (((((kh) * 4 + g_) ^ (c_ & 7))) << 3)])

  for (int kb = 0; kb < K; kb += 64) {
    __syncthreads();
#pragma unroll
    for (int i = 0; i < 2; ++i) {
      int f = t + i * 256;            // 512 uint4 per matrix tile
      int r = f >> 3, ch = f & 7;
      *(uint4*)&As[r * 64 + ((ch ^ (r & 7)) << 3)] =
          *(const uint4*)&A[(size_t)(mb + r) * K + kb + ch * 8];
      *(uint4*)&Bs[r * 64 + ((ch ^ (r & 7)) << 3)] =
          *(const uint4*)&B[(size_t)(jb + r) * K + kb + ch * 8];
    }
    __syncthreads();
#pragma unroll
    for (int kh = 0; kh < 2; ++kh) {
      half8 a0 = FRAG16(As, m0 + c_, kh);
      half8 a1 = FRAG16(As, m0 + 16 + c_, kh);
      half8 b0 = FRAG16(Bs, n0 + c_, kh);
      half8 b1 = FRAG16(Bs, n0 + 16 + c_, kh);
      acc[0][0] = __builtin_amdgcn_mfma_f32_16x16x32_f16(a0, b0, acc[0][0], 0, 0, 0);
      acc[0][1] = __builtin_amdgcn_mfma_f32_16x16x32_f16(a0, b1, acc[0][1], 0, 0, 0);
      acc[1][0] = __builtin_amdgcn_mfma_f32_16x16x32_f16(a1, b0, acc[1][0], 0, 0, 0);
      acc[1][1] = __builtin_amdgcn_mfma_f32_16x16x32_f16(a1, b1, acc[1][1], 0, 0, 0);
    }
  }
#undef FRAG16

#pragma unroll
  for (int mt = 0; mt < 2; ++mt)
#pragma unroll
    for (int nt = 0; nt < 2; ++nt) {
      int mbase = mb + m0 + mt * 16 + g_ * 4;
      int jj    = jb + n0 + nt * 16 + c_;
      if (EPI == 0 || EPI == 1) {
        f16* out = (f16*)outv;
        float bc = bias[jj];
#pragma unroll
        for (int r = 0; r < 4; ++r) {
          float v = (acc[mt][nt][r] + bc) * alpha;
          if (EPI == 1) v = fmaxf(v, 0.f);
          out[(size_t)(mbase + r) * J + jj] = (f16)v;
        }
      } else if (EPI == 2) {
        f16* out = (f16*)outv;
#pragma unroll
        for (int r = 0; r < 4; ++r)
          out[(size_t)(mbase + r) * J + jj] = (f16)(acc[mt][nt][r] + bias[mbase + r]);
      } else {
        float* out = (float*)outv;
        float bc = bias[jj];
#pragma unroll
        for (int r = 0; r < 4; ++r) {
          int m = mbase + r;
          out[(size_t)m * J + jj] = acc[mt][nt][r] + bc +
              resid[(size_t)m * J + jj] + c2n[lab[m] * 128 + jj];
        }
      }
    }
}

// ---------------------------------------------------------------- MFMA flash attention
// Waves split d (not q) in PV: P is shared through LDS, V fragments read once per block.
// qg,kg: f16 [N][128] (col = h*32+e, q pre-scaled by 1/sqrt(32))
// vt:    f16 [H*256][4096] (V transposed)
// Partials: pO f16 [s][1024 j][4096 q] (normalized), pM/pL f32 [s][4][4096]
__global__ __launch_bounds__(256, 3) void k_attn_mfma(const f16* __restrict__ qg,
                                                      const f16* __restrict__ kg,
                                                      const f16* __restrict__ vt,
                                                      f16* __restrict__ pO,
                                                      float* __restrict__ pM,
                                                      float* __restrict__ pL) {
  const int hd  = blockIdx.y;
  const int sp  = blockIdx.z;
  const int kv0 = sp * KVRANGE;
  const int t   = threadIdx.x;
  const int w   = t >> 6, l = t & 63;
  const int g   = l >> 4, c = l & 15;
  const int qb  = blockIdx.x * 64;     // block owns 64 q

  __shared__ f16 Ks[32 * 40];          // [kv][e] pad 40
  __shared__ f16 Vs[256 * 40];         // [d][kv] pad 40
  __shared__ f16 Ps[64 * 40];          // [q][kv] pad 40 (B-frag layout)
  __shared__ float CfS[64];            // per-q rescale factor (then final l)

  // Q fragment for this wave's q-group (q = qb + w*16 + c)
  half8 qf = *(const half8*)&qg[(size_t)(qb + w * 16 + c) * 128 + hd * 32 + g * 8];

  f32x4 oacc[4][4];                    // [dt_local][qt]; d = (w*4+i)*16+g*4+r, q = qb+qt*16+c
#pragma unroll
  for (int i = 0; i < 4; ++i)
#pragma unroll
    for (int j = 0; j < 4; ++j) oacc[i][j] = (f32x4){0.f, 0.f, 0.f, 0.f};
  float m_run = -INFINITY, l_run = 0.f;
  const f32x4 zero4 = {0.f, 0.f, 0.f, 0.f};

  for (int kb = 0; kb < KVRANGE; kb += 32) {
    __syncthreads();   // prev PV / CfS reads complete before tiles are overwritten
    if (t < 128) {     // K tile: 32 x 32 f16 = 128 uint4
      int r = t >> 2, c8 = (t & 3) * 8;
      *(uint4*)&Ks[r * 40 + c8] =
          *(const uint4*)&kg[(size_t)(kv0 + kb + r) * 128 + hd * 32 + c8];
    }
#pragma unroll
    for (int i = 0; i < 4; ++i) {      // V^T tile: 256 x 32 f16 = 1024 uint4
      int cc = i * 256 + t, d = cc >> 2, c8 = (cc & 3) * 8;
      *(uint4*)&Vs[d * 40 + c8] =
          *(const uint4*)&vt[(size_t)(hd * 256 + d) * 4096 + kv0 + kb + c8];
    }
    __syncthreads();   // tiles ready

    // ---- QK^T for this wave's 16 q (swapped: S^T tile, lane reg r -> kv = g*4+r / +16)
    f32x4 s0 = __builtin_amdgcn_mfma_f32_16x16x32_f16(
        *(const half8*)&Ks[(c) * 40 + g * 8], qf, zero4, 0, 0, 0);
    f32x4 s1 = __builtin_amdgcn_mfma_f32_16x16x32_f16(
        *(const half8*)&Ks[(16 + c) * 40 + g * 8], qf, zero4, 0, 0, 0);

    float sv[8];
#pragma unroll
    for (int r = 0; r < 4; ++r) {
      float a = s0[r]; sv[r]     = a > 0.f ? a : 0.2f * a;   // leaky(0.2), scale in q
      float b = s1[r]; sv[4 + r] = b > 0.f ? b : 0.2f * b;
    }
    float mx = sv[0];
#pragma unroll
    for (int r = 1; r < 8; ++r) mx = fmaxf(mx, sv[r]);
    mx = fmaxf(mx, __shfl_xor(mx, 16));
    mx = fmaxf(mx, __shfl_xor(mx, 32));

    float cf = 1.f;
    if (!__all(mx <= m_run + 8.f)) {   // defer-max
      float m_new = fmaxf(m_run, mx);
      cf = __expf(m_run - m_new);
      m_run = m_new;
    }
    float p[8], ps = 0.f;
#pragma unroll
    for (int r = 0; r < 8; ++r) { p[r] = __expf(sv[r] - m_run); ps += p[r]; }
    ps += __shfl_xor(ps, 16);
    ps += __shfl_xor(ps, 32);
    l_run = l_run * cf + ps;

    if (g == 0) CfS[w * 16 + c] = cf;
    // pack P -> Ps[q][kv] (pairs are kv-consecutive: reg r -> kv g*4+r, +16)
    {
      union { unsigned u; f16 h2[2]; } z;
      uint2 lo, hi;
      z.h2[0] = (f16)p[0]; z.h2[1] = (f16)p[1]; lo.x = z.u;
      z.h2[0] = (f16)p[2]; z.h2[1] = (f16)p[3]; lo.y = z.u;
      z.h2[0] = (f16)p[4]; z.h2[1] = (f16)p[5]; hi.x = z.u;
      z.h2[0] = (f16)p[6]; z.h2[1] = (f16)p[7]; hi.y = z.u;
      *(uint2*)&Ps[(w * 16 + c) * 40 + g * 4]      = lo;
      *(uint2*)&Ps[(w * 16 + c) * 40 + 16 + g * 4] = hi;
    }
    __syncthreads();   // P + Cf ready

    // ---- rescale accumulators by per-q cf
#pragma unroll
    for (int qt = 0; qt < 4; ++qt) {
      float cfq = CfS[qt * 16 + c];
      if (!__all(cfq == 1.f)) {
#pragma unroll
        for (int i = 0; i < 4; ++i) {
          oacc[i][qt][0] *= cfq; oacc[i][qt][1] *= cfq;
          oacc[i][qt][2] *= cfq; oacc[i][qt][3] *= cfq;
        }
      }
    }
    // ---- PV: this wave's d-slice (dt = w*4+i), all 4 q-tiles
    half8 pfr[4];
#pragma unroll
    for (int qt = 0; qt < 4; ++qt)
      pfr[qt] = *(const half8*)&Ps[(qt * 16 + c) * 40 + g * 8];
#pragma unroll
    for (int i = 0; i < 4; ++i) {
      half8 vfr = *(const half8*)&Vs[((w * 4 + i) * 16 + c) * 40 + g * 8];
#pragma unroll
      for (int qt = 0; qt < 4; ++qt)
        oacc[i][qt] = __builtin_amdgcn_mfma_f32_16x16x32_f16(vfr, pfr[qt], oacc[i][qt], 0, 0, 0);
    }
  }

  // broadcast final l per q, then write normalized partials
  __syncthreads();
  if (g == 0) CfS[w * 16 + c] = l_run;
  __syncthreads();
  float linv[4];
#pragma unroll
  for (int qt = 0; qt < 4; ++qt) linv[qt] = 1.f / CfS[qt * 16 + c];
#pragma unroll
  for (int i = 0; i < 4; ++i)
#pragma unroll
    for (int qt = 0; qt < 4; ++qt)
#pragma unroll
      for (int r = 0; r < 4; ++r) {
        int j = hd * 256 + (w * 4 + i) * 16 + g * 4 + r;
        pO[(size_t)(sp * 1024 + j) * 4096 + qb + qt * 16 + c] =
            (f16)(oacc[i][qt][r] * linv[qt]);
      }
  if (g == 0) {
    pM[(sp * 4 + hd) * 4096 + qb + w * 16 + c] = m_run;
    pL[(sp * 4 + hd) * 4096 + qb + w * 16 + c] = l_run;
  }
}

// ---------------------------------------------------------------- split-K merge -> hp16 [4096][1024]
__global__ __launch_bounds__(256) void k_merge(const f16* __restrict__ pO,
                                               const float* __restrict__ pM,
                                               const float* __restrict__ pL,
                                               f16* __restrict__ hp) {
  const int q0 = blockIdx.x * 64, jb = blockIdx.y * 64;
  const int h  = jb >> 8;
  const int t  = threadIdx.x;
  __shared__ float wm[NSPLIT][64], wl[NSPLIT][64];
  __shared__ float tile[64][65];

  if (t < 64) {
#pragma unroll
    for (int s = 0; s < NSPLIT; ++s) {
      wm[s][t] = pM[(s * 4 + h) * 4096 + q0 + t];
      wl[s][t] = pL[(s * 4 + h) * 4096 + q0 + t];
    }
  }
  __syncthreads();

  const int q8 = (t & 7) * 8;
#pragma unroll
  for (int it = 0; it < 2; ++it) {
    int jl = (t >> 3) + it * 32;
    float wgt[NSPLIT][8], inv[8];
#pragma unroll
    for (int q = 0; q < 8; ++q) {
      float M = wm[0][q8 + q];
#pragma unroll
      for (int s = 1; s < NSPLIT; ++s) M = fmaxf(M, wm[s][q8 + q]);
      float den = 0.f;
#pragma unroll
      for (int s = 0; s < NSPLIT; ++s) {
        float wv = wl[s][q8 + q] * __expf(wm[s][q8 + q] - M);
        wgt[s][q] = wv; den += wv;
      }
      inv[q] = 1.f / den;
    }
    float o[8] = {0.f};
#pragma unroll
    for (int s = 0; s < NSPLIT; ++s) {
      union { uint4 u; f16 h8[8]; } raw;
      raw.u = *(const uint4*)&pO[(size_t)(s * 1024 + jb + jl) * 4096 + q0 + q8];
#pragma unroll
      for (int q = 0; q < 8; ++q) o[q] += wgt[s][q] * (float)raw.h8[q];
    }
#pragma unroll
    for (int q = 0; q < 8; ++q) tile[q8 + q][jl] = o[q] * inv[q];
  }
  __syncthreads();

#pragma unroll
  for (int it = 0; it < 2; ++it) {
    int ql = (t >> 3) + it * 32, chk = t & 7;
    union { uint4 u; f16 h8[8]; } pk;
#pragma unroll
    for (int k = 0; k < 8; ++k) pk.h8[k] = (f16)tile[ql][chk * 8 + k];
    *(uint4*)&hp[(size_t)(q0 + ql) * 1024 + jb + chk * 8] = pk.u;
  }
}

// ---------------------------------------------------------------- misc small kernels
__global__ void k_zero(float* __restrict__ p, int n) {
  int i = blockIdx.x * blockDim.x + threadIdx.x;
  if (i < n) p[i] = 0.f;
}

__global__ __launch_bounds__(256) void k_segsum(const float* __restrict__ h,
                                                const int* __restrict__ lab,
                                                float* __restrict__ sums,
                                                float* __restrict__ cnt) {
  int i = blockIdx.x * blockDim.x + threadIdx.x;  // N*128
  int n = i >> 7, d = i & 127;
  int c = lab[n];
  atomicAdd(&sums[c * 128 + d], h[i]);
  if (d == 0) atomicAdd(&cnt[c], 1.0f);
}

__global__ __launch_bounds__(128) void k_gru(const float* __restrict__ sums,
                                             const float* __restrict__ cnt,
                                             const float* __restrict__ ch,
                                             const float* __restrict__ Wih,
                                             const float* __restrict__ bih,
                                             const float* __restrict__ Whh,
                                             const float* __restrict__ bhh,
                                             float* __restrict__ uch,
                                             float* __restrict__ out_uch) {
  int c = blockIdx.x, d = threadIdx.x;
  __shared__ float ax[128], hx[128];
  float count = cnt[c];
  ax[d] = sums[c * 128 + d] / fmaxf(count, 1.0f);
  hx[d] = ch[c * 128 + d];
  __syncthreads();
  float gi[3], gh[3];
#pragma unroll
  for (int g = 0; g < 3; ++g) {
    const float4* wi4 = (const float4*)&Wih[(size_t)(g * 128 + d) * 128];
    const float4* wh4 = (const float4*)&Whh[(size_t)(g * 128 + d) * 128];
    float si = 0.f, sh = 0.f;
#pragma unroll 8
    for (int e = 0; e < 32; ++e) {
      float4 wv = wi4[e], hv = wh4[e];
      si = fmaf(ax[e*4+0], wv.x, si); si = fmaf(ax[e*4+1], wv.y, si);
      si = fmaf(ax[e*4+2], wv.z, si); si = fmaf(ax[e*4+3], wv.w, si);
      sh = fmaf(hx[e*4+0], hv.x, sh); sh = fmaf(hx[e*4+1], hv.y, sh);
      sh = fmaf(hx[e*4+2], hv.z, sh); sh = fmaf(hx[e*4+3], hv.w, sh);
    }
    gi[g] = si + bih[g * 128 + d];
    gh[g] = sh + bhh[g * 128 + d];
  }
  float r = 1.f / (1.f + expf(-(gi[0] + gh[0])));
  float z = 1.f / (1.f + expf(-(gi[1] + gh[1])));
  float nn = tanhf(gi[2] + r * gh[2]);
  float hv = hx[d];
  float nh = (1.f - z) * nn + z * hv;
  float res = (count > 0.f) ? nh : hv;
  uch[c * 128 + d] = res;
  out_uch[c * 128 + d] = res;
}

__global__ __launch_bounds__(128) void k_c2n(const float* __restrict__ uch,
                                             const float* __restrict__ Wp,
                                             const float* __restrict__ bp,
                                             float* __restrict__ c2n) {
  int c = blockIdx.x, d = threadIdx.x;
  __shared__ float u[128];
  u[d] = uch[c * 128 + d];
  __syncthreads();
  const float4* w4 = (const float4*)&Wp[(size_t)d * 128];
  float s = 0.f;
#pragma unroll 8
  for (int e = 0; e < 32; ++e) {
    float4 wv = w4[e];
    s = fmaf(u[e*4+0], wv.x, s); s = fmaf(u[e*4+1], wv.y, s);
    s = fmaf(u[e*4+2], wv.z, s); s = fmaf(u[e*4+3], wv.w, s);
  }
  c2n[c * 128 + d] = s + bp[d];
}

// ---------------------------------------------------------------- launch
extern "C" void kernel_launch(void* const* d_in, const int* in_sizes, int n_in,
                              void* d_out, int out_size, void* d_ws, size_t ws_size,
                              hipStream_t stream) {
  const float* x    = (const float*)d_in[0];
  const float* h    = (const float*)d_in[1];
  const float* ch   = (const float*)d_in[2];
  const int*   lab  = (const int*)d_in[4];
  const float* Wq   = (const float*)d_in[8];
  const float* bq   = (const float*)d_in[9];
  const float* Wk   = (const float*)d_in[10];
  const float* bk   = (const float*)d_in[11];
  const float* Wv   = (const float*)d_in[12];
  const float* bv   = (const float*)d_in[13];
  const float* W1   = (const float*)d_in[14];
  const float* b1   = (const float*)d_in[15];
  const float* W2   = (const float*)d_in[16];
  const float* b2   = (const float*)d_in[17];
  const float* gWih = (const float*)d_in[18];
  const float* gbih = (const float*)d_in[19];
  const float* gWhh = (const float*)d_in[20];
  const float* gbhh = (const float*)d_in[21];
  const float* Wp   = (const float*)d_in[22];
  const float* bp   = (const float*)d_in[23];

  float* outp    = (float*)d_out;                 // [4096*128] updated_h
  float* out_uch = outp + 4096 * 128;             // [64*128] updated_cluster_h

  // ---- workspace layout
  f16* comb16 = (f16*)d_ws;                        // 4096*256
  f16* w16    = comb16 + 4096 * 256;               // 655360
  f16* wq16   = w16;                               //  32768
  f16* wk16   = w16 + 32768;
  f16* wv16   = w16 + 65536;                       // 262144 [1024][256]
  f16* w116   = w16 + 327680;                      // 262144 [256][1024]
  f16* w216   = w16 + 589824;                      //  65536 [256][256]
  f16* qf16   = w16 + 655360;                      // 4096*128
  f16* kf16   = qf16 + 4096 * 128;                 // 4096*128
  f16* vt16   = kf16 + 4096 * 128;                 // 1024*4096
  f16* pO     = vt16 + 1024 * 4096;                // 4*1024*4096
  f16* hp16   = pO + (size_t)NSPLIT * 1024 * 4096; // 4096*1024
  f16* y116   = hp16 + (size_t)4096 * 1024;        // 4096*256
  float* pM   = (float*)(y116 + 4096 * 256);       // 4*4*4096
  float* pL   = pM + NSPLIT * 4 * 4096;
  float* sums = pL + NSPLIT * 4 * 4096;            // 8192
  float* cnt  = sums + 64 * 128;                   // 64
  float* uch  = cnt + 64;                          // 8192
  float* c2n  = uch + 64 * 128;                    // 8192

  const float qscale = 0.17677669529663687f;       // 1/sqrt(32)

  // combined (f16) + weight conversion
  k_combined<<<1024, 256, 0, stream>>>(x, h, comb16);
  k_w2h<<<640, 256, 0, stream>>>(Wq, Wk, Wv, W1, W2, w16);
  // projections (MFMA): Q (scaled), K, V^T (swapped operands, row-bias)
  k_gemm16<0><<<dim3(64, 2),  256, 0, stream>>>(comb16, wq16, bq, nullptr, nullptr, nullptr, qf16, 4096, 256, 128,  qscale);
  k_gemm16<0><<<dim3(64, 2),  256, 0, stream>>>(comb16, wk16, bk, nullptr, nullptr, nullptr, kf16, 4096, 256, 128,  1.0f);
  k_gemm16<2><<<dim3(16, 64), 256, 0, stream>>>(wv16, comb16, bv, nullptr, nullptr, nullptr, vt16, 1024, 256, 4096, 1.0f);
  // flash attention (split-K) + merge -> hp16 [4096][1024]
  k_attn_mfma<<<dim3(64, NHEADS, NSPLIT), 256, 0, stream>>>(qf16, kf16, vt16, pO, pM, pL);
  k_merge<<<dim3(64, 16), 256, 0, stream>>>(pO, pM, pL, hp16);
  // MLP1
  k_gemm16<1><<<dim3(64, 4), 256, 0, stream>>>(hp16, w116, b1, nullptr, nullptr, nullptr, y116, 4096, 1024, 256, 1.0f);
  // cluster aggregation chain (needed by fused MLP2 epilogue)
  k_zero<<<33, 256, 0, stream>>>(sums, 64 * 128 + 64);
  k_segsum<<<2048, 256, 0, stream>>>(h, lab, sums, cnt);
  k_gru<<<64, 128, 0, stream>>>(sums, cnt, ch, gWih, gbih, gWhh, gbhh, uch, out_uch);
  k_c2n<<<64, 128, 0, stream>>>(uch, Wp, bp, c2n);
  // MLP2 (cols 128..255 only) fused with +h resid and +c2n[lab] -> final output
  k_gemm16<3><<<dim3(64, 2), 256, 0, stream>>>(y116, w216 + 128 * 256, b2 + 128, h, lab, c2n, outp, 4096, 256, 128, 1.0f);
}

// Round 7
// 259.500 us; speedup vs baseline: 7.2136x; 1.0437x over previous
//
#include <hip/hip_runtime.h>
#include <math.h>

#define N_NODES 4096
#define NHEADS  4
#define NSPLIT  4
#define KVRANGE 1024   // 4096 / NSPLIT

typedef _Float16 f16;
typedef _Float16 half8 __attribute__((ext_vector_type(8)));
typedef float f32x4 __attribute__((ext_vector_type(4)));

// ---------------------------------------------------------------- GEMM body (f16 in, f32 acc)
// out[m][j] = sum_k A[m][k] * B[j][k] (+ bias) ; A [M][K], B [J][K] f16, K % 64 == 0
// EPI: 0 f16 out, col-bias, *alpha   1 f16 out, col-bias, relu
//      2 f16 out, row-bias           3 f32 out, col-bias, + resid + c2n[lab[m]]
template <int EPI>
__device__ __forceinline__ void gemm_body(const f16* __restrict__ A,
                                          const f16* __restrict__ B,
                                          const float* __restrict__ bias,
                                          const float* __restrict__ resid,
                                          const int* __restrict__ lab,
                                          const float* __restrict__ c2n,
                                          void* __restrict__ outv,
                                          int M, int K, int J, float alpha,
                                          int bx, int by, f16* smem) {
  f16* As = smem;             // 64 rows x 128B, XOR-swizzled chunks
  f16* Bs = smem + 64 * 64;
  const int t  = threadIdx.x;
  const int mb = bx * 64, jb = by * 64;
  const int w  = t >> 6, l = t & 63;
  const int g_ = l >> 4, c_ = l & 15;
  const int m0 = (w >> 1) * 32, n0 = (w & 1) * 32;

  f32x4 acc[2][2];
#pragma unroll
  for (int i = 0; i < 2; ++i)
#pragma unroll
    for (int j = 0; j < 2; ++j) acc[i][j] = (f32x4){0.f, 0.f, 0.f, 0.f};

#define FRAG16(BUF, row, kh) \
  (*(const half8*)&BUF[(size_t)(row) * 64 + (((((kh) * 4 + g_) ^ (c_ & 7))) << 3)])

  for (int kb = 0; kb < K; kb += 64) {
    __syncthreads();
#pragma unroll
    for (int i = 0; i < 2; ++i) {
      int f = t + i * 256;            // 512 uint4 per matrix tile
      int r = f >> 3, ch = f & 7;
      *(uint4*)&As[r * 64 + ((ch ^ (r & 7)) << 3)] =
          *(const uint4*)&A[(size_t)(mb + r) * K + kb + ch * 8];
      *(uint4*)&Bs[r * 64 + ((ch ^ (r & 7)) << 3)] =
          *(const uint4*)&B[(size_t)(jb + r) * K + kb + ch * 8];
    }
    __syncthreads();
#pragma unroll
    for (int kh = 0; kh < 2; ++kh) {
      half8 a0 = FRAG16(As, m0 + c_, kh);
      half8 a1 = FRAG16(As, m0 + 16 + c_, kh);
      half8 b0 = FRAG16(Bs, n0 + c_, kh);
      half8 b1 = FRAG16(Bs, n0 + 16 + c_, kh);
      acc[0][0] = __builtin_amdgcn_mfma_f32_16x16x32_f16(a0, b0, acc[0][0], 0, 0, 0);
      acc[0][1] = __builtin_amdgcn_mfma_f32_16x16x32_f16(a0, b1, acc[0][1], 0, 0, 0);
      acc[1][0] = __builtin_amdgcn_mfma_f32_16x16x32_f16(a1, b0, acc[1][0], 0, 0, 0);
      acc[1][1] = __builtin_amdgcn_mfma_f32_16x16x32_f16(a1, b1, acc[1][1], 0, 0, 0);
    }
  }
#undef FRAG16

#pragma unroll
  for (int mt = 0; mt < 2; ++mt)
#pragma unroll
    for (int nt = 0; nt < 2; ++nt) {
      int mbase = mb + m0 + mt * 16 + g_ * 4;
      int jj    = jb + n0 + nt * 16 + c_;
      if (EPI == 0 || EPI == 1) {
        f16* out = (f16*)outv;
        float bc = bias[jj];
#pragma unroll
        for (int r = 0; r < 4; ++r) {
          float v = (acc[mt][nt][r] + bc) * alpha;
          if (EPI == 1) v = fmaxf(v, 0.f);
          out[(size_t)(mbase + r) * J + jj] = (f16)v;
        }
      } else if (EPI == 2) {
        f16* out = (f16*)outv;
#pragma unroll
        for (int r = 0; r < 4; ++r)
          out[(size_t)(mbase + r) * J + jj] = (f16)(acc[mt][nt][r] + bias[mbase + r]);
      } else {
        float* out = (float*)outv;
        float bc = bias[jj];
#pragma unroll
        for (int r = 0; r < 4; ++r) {
          int m = mbase + r;
          out[(size_t)m * J + jj] = acc[mt][nt][r] + bc +
              resid[(size_t)m * J + jj] + c2n[lab[m] * 128 + jj];
        }
      }
    }
}

template <int EPI>
__global__ __launch_bounds__(256) void k_gemm16(const f16* __restrict__ A,
                                                const f16* __restrict__ B,
                                                const float* __restrict__ bias,
                                                const float* __restrict__ resid,
                                                const int* __restrict__ lab,
                                                const float* __restrict__ c2n,
                                                void* __restrict__ outv,
                                                int M, int K, int J, float alpha) {
  __shared__ f16 smem[2 * 64 * 64];
  gemm_body<EPI>(A, B, bias, resid, lab, c2n, outv, M, K, J, alpha,
                 blockIdx.x, blockIdx.y, smem);
}

// ---------------------------------------------------------------- prep: combined + w2h + zero
// pool: [Wq 32768][Wk 32768][Wv 262144][W1 262144][W2 65536] = 655360
__global__ __launch_bounds__(256) void k_prep(const float* __restrict__ x,
                                              const float* __restrict__ h,
                                              const float* __restrict__ Wq,
                                              const float* __restrict__ Wk,
                                              const float* __restrict__ Wv,
                                              const float* __restrict__ W1,
                                              const float* __restrict__ W2,
                                              f16* __restrict__ comb16,
                                              f16* __restrict__ pool,
                                              float* __restrict__ sums) {
  const int b = blockIdx.x, t = threadIdx.x;
  if (b < 1024) {                      // combined = [x, h] -> f16
    int i = b * 256 + t;               // over N*64 float4
    int n = i >> 6, c = i & 63;
    float4 v;
    if (c < 32) v = ((const float4*)x)[n * 32 + c];
    else        v = ((const float4*)h)[n * 32 + (c - 32)];
    union { uint2 u; f16 h4[4]; } pk;
    pk.h4[0] = (f16)v.x; pk.h4[1] = (f16)v.y; pk.h4[2] = (f16)v.z; pk.h4[3] = (f16)v.w;
    *(uint2*)&comb16[(size_t)i * 4] = pk.u;
  } else if (b < 1664) {               // weights -> f16
    int i4 = ((b - 1024) * 256 + t) * 4;
    const float* src; int off;
    if      (i4 <  32768) { src = Wq; off = 0; }
    else if (i4 <  65536) { src = Wk; off = 32768; }
    else if (i4 < 327680) { src = Wv; off = 65536; }
    else if (i4 < 589824) { src = W1; off = 327680; }
    else                  { src = W2; off = 589824; }
    float4 v = *(const float4*)&src[i4 - off];
    union { uint2 u; f16 h4[4]; } pk;
    pk.h4[0] = (f16)v.x; pk.h4[1] = (f16)v.y; pk.h4[2] = (f16)v.z; pk.h4[3] = (f16)v.w;
    *(uint2*)&pool[i4] = pk.u;
  } else {                             // zero sums[8192] + cnt[64] (contiguous)
    int i = (b - 1664) * 256 + t;
    if (i < 8256) sums[i] = 0.f;
  }
}

// ---------------------------------------------------------------- qkv: V-proj | Q-proj | K-proj | segsum
__global__ __launch_bounds__(256) void k_qkv(const f16* __restrict__ comb16,
                                             const f16* __restrict__ wq16,
                                             const f16* __restrict__ wk16,
                                             const f16* __restrict__ wv16,
                                             const float* __restrict__ bq,
                                             const float* __restrict__ bk,
                                             const float* __restrict__ bv,
                                             f16* __restrict__ qf16,
                                             f16* __restrict__ kf16,
                                             f16* __restrict__ vt16,
                                             const float* __restrict__ h,
                                             const int* __restrict__ lab,
                                             float* __restrict__ sums,
                                             float* __restrict__ cnt,
                                             float qscale) {
  __shared__ f16 smem[2 * 64 * 64];
  const int b = blockIdx.x;
  if (b < 1024) {            // V^T: A = Wv [1024][256], B = comb -> vt [1024][4096]
    gemm_body<2>(wv16, comb16, bv, nullptr, nullptr, nullptr, vt16,
                 1024, 256, 4096, 1.0f, b & 15, b >> 4, smem);
  } else if (b < 1152) {     // Q (pre-scaled)
    int r = b - 1024;
    gemm_body<0>(comb16, wq16, bq, nullptr, nullptr, nullptr, qf16,
                 4096, 256, 128, qscale, r & 63, r >> 6, smem);
  } else if (b < 1280) {     // K
    int r = b - 1152;
    gemm_body<0>(comb16, wk16, bk, nullptr, nullptr, nullptr, kf16,
                 4096, 256, 128, 1.0f, r & 63, r >> 6, smem);
  } else {                   // segment sum over h
    int i = (b - 1280) * 256 + threadIdx.x;   // N*128
    int n = i >> 7, d = i & 127;
    int c = lab[n];
    atomicAdd(&sums[c * 128 + d], h[i]);
    if (d == 0) atomicAdd(&cnt[c], 1.0f);
  }
}

// ---------------------------------------------------------------- MFMA flash attention
// Waves split d (not q) in PV: P is shared through LDS, V fragments read once per block.
// qg,kg: f16 [N][128] (col = h*32+e, q pre-scaled by 1/sqrt(32))
// vt:    f16 [H*256][4096] (V transposed)
// Partials: pO f16 [s][1024 j][4096 q] (normalized), pM/pL f32 [s][4][4096]
__global__ __launch_bounds__(256, 3) void k_attn_mfma(const f16* __restrict__ qg,
                                                      const f16* __restrict__ kg,
                                                      const f16* __restrict__ vt,
                                                      f16* __restrict__ pO,
                                                      float* __restrict__ pM,
                                                      float* __restrict__ pL) {
  const int hd  = blockIdx.y;
  const int sp  = blockIdx.z;
  const int kv0 = sp * KVRANGE;
  const int t   = threadIdx.x;
  const int w   = t >> 6, l = t & 63;
  const int g   = l >> 4, c = l & 15;
  const int qb  = blockIdx.x * 64;     // block owns 64 q

  __shared__ f16 Ks[32 * 40];          // [kv][e] pad 40
  __shared__ f16 Vs[256 * 40];         // [d][kv] pad 40
  __shared__ f16 Ps[64 * 40];          // [q][kv] pad 40 (B-frag layout)
  __shared__ float CfS[64];            // per-q rescale factor (then final l)

  // Q fragment for this wave's q-group (q = qb + w*16 + c)
  half8 qf = *(const half8*)&qg[(size_t)(qb + w * 16 + c) * 128 + hd * 32 + g * 8];

  f32x4 oacc[4][4];                    // [dt_local][qt]; d = (w*4+i)*16+g*4+r, q = qb+qt*16+c
#pragma unroll
  for (int i = 0; i < 4; ++i)
#pragma unroll
    for (int j = 0; j < 4; ++j) oacc[i][j] = (f32x4){0.f, 0.f, 0.f, 0.f};
  float m_run = -INFINITY, l_run = 0.f;
  const f32x4 zero4 = {0.f, 0.f, 0.f, 0.f};

  for (int kb = 0; kb < KVRANGE; kb += 32) {
    __syncthreads();   // prev PV / CfS reads complete before tiles are overwritten
    if (t < 128) {     // K tile: 32 x 32 f16 = 128 uint4
      int r = t >> 2, c8 = (t & 3) * 8;
      *(uint4*)&Ks[r * 40 + c8] =
          *(const uint4*)&kg[(size_t)(kv0 + kb + r) * 128 + hd * 32 + c8];
    }
#pragma unroll
    for (int i = 0; i < 4; ++i) {      // V^T tile: 256 x 32 f16 = 1024 uint4
      int cc = i * 256 + t, d = cc >> 2, c8 = (cc & 3) * 8;
      *(uint4*)&Vs[d * 40 + c8] =
          *(const uint4*)&vt[(size_t)(hd * 256 + d) * 4096 + kv0 + kb + c8];
    }
    __syncthreads();   // tiles ready

    // ---- QK^T for this wave's 16 q (swapped: S^T tile, lane reg r -> kv = g*4+r / +16)
    f32x4 s0 = __builtin_amdgcn_mfma_f32_16x16x32_f16(
        *(const half8*)&Ks[(c) * 40 + g * 8], qf, zero4, 0, 0, 0);
    f32x4 s1 = __builtin_amdgcn_mfma_f32_16x16x32_f16(
        *(const half8*)&Ks[(16 + c) * 40 + g * 8], qf, zero4, 0, 0, 0);

    float sv[8];
#pragma unroll
    for (int r = 0; r < 4; ++r) {
      float a = s0[r]; sv[r]     = a > 0.f ? a : 0.2f * a;   // leaky(0.2), scale in q
      float b = s1[r]; sv[4 + r] = b > 0.f ? b : 0.2f * b;
    }
    float mx = sv[0];
#pragma unroll
    for (int r = 1; r < 8; ++r) mx = fmaxf(mx, sv[r]);
    mx = fmaxf(mx, __shfl_xor(mx, 16));
    mx = fmaxf(mx, __shfl_xor(mx, 32));

    float cf = 1.f;
    if (!__all(mx <= m_run + 8.f)) {   // defer-max
      float m_new = fmaxf(m_run, mx);
      cf = __expf(m_run - m_new);
      m_run = m_new;
    }
    float p[8], ps = 0.f;
#pragma unroll
    for (int r = 0; r < 8; ++r) { p[r] = __expf(sv[r] - m_run); ps += p[r]; }
    ps += __shfl_xor(ps, 16);
    ps += __shfl_xor(ps, 32);
    l_run = l_run * cf + ps;

    if (g == 0) CfS[w * 16 + c] = cf;
    // pack P -> Ps[q][kv] (pairs are kv-consecutive: reg r -> kv g*4+r, +16)
    {
      union { unsigned u; f16 h2[2]; } z;
      uint2 lo, hi;
      z.h2[0] = (f16)p[0]; z.h2[1] = (f16)p[1]; lo.x = z.u;
      z.h2[0] = (f16)p[2]; z.h2[1] = (f16)p[3]; lo.y = z.u;
      z.h2[0] = (f16)p[4]; z.h2[1] = (f16)p[5]; hi.x = z.u;
      z.h2[0] = (f16)p[6]; z.h2[1] = (f16)p[7]; hi.y = z.u;
      *(uint2*)&Ps[(w * 16 + c) * 40 + g * 4]      = lo;
      *(uint2*)&Ps[(w * 16 + c) * 40 + 16 + g * 4] = hi;
    }
    __syncthreads();   // P + Cf ready

    // ---- rescale accumulators by per-q cf
#pragma unroll
    for (int qt = 0; qt < 4; ++qt) {
      float cfq = CfS[qt * 16 + c];
      if (!__all(cfq == 1.f)) {
#pragma unroll
        for (int i = 0; i < 4; ++i) {
          oacc[i][qt][0] *= cfq; oacc[i][qt][1] *= cfq;
          oacc[i][qt][2] *= cfq; oacc[i][qt][3] *= cfq;
        }
      }
    }
    // ---- PV: this wave's d-slice (dt = w*4+i), all 4 q-tiles
    half8 pfr[4];
#pragma unroll
    for (int qt = 0; qt < 4; ++qt)
      pfr[qt] = *(const half8*)&Ps[(qt * 16 + c) * 40 + g * 8];
#pragma unroll
    for (int i = 0; i < 4; ++i) {
      half8 vfr = *(const half8*)&Vs[((w * 4 + i) * 16 + c) * 40 + g * 8];
#pragma unroll
      for (int qt = 0; qt < 4; ++qt)
        oacc[i][qt] = __builtin_amdgcn_mfma_f32_16x16x32_f16(vfr, pfr[qt], oacc[i][qt], 0, 0, 0);
    }
  }

  // broadcast final l per q, then write normalized partials
  __syncthreads();
  if (g == 0) CfS[w * 16 + c] = l_run;
  __syncthreads();
  float linv[4];
#pragma unroll
  for (int qt = 0; qt < 4; ++qt) linv[qt] = 1.f / CfS[qt * 16 + c];
#pragma unroll
  for (int i = 0; i < 4; ++i)
#pragma unroll
    for (int qt = 0; qt < 4; ++qt)
#pragma unroll
      for (int r = 0; r < 4; ++r) {
        int j = hd * 256 + (w * 4 + i) * 16 + g * 4 + r;
        pO[(size_t)(sp * 1024 + j) * 4096 + qb + qt * 16 + c] =
            (f16)(oacc[i][qt][r] * linv[qt]);
      }
  if (g == 0) {
    pM[(sp * 4 + hd) * 4096 + qb + w * 16 + c] = m_run;
    pL[(sp * 4 + hd) * 4096 + qb + w * 16 + c] = l_run;
  }
}

// ---------------------------------------------------------------- merge + fused GRU->c2n
__global__ __launch_bounds__(256) void k_mergeplus(const f16* __restrict__ pO,
                                                   const float* __restrict__ pM,
                                                   const float* __restrict__ pL,
                                                   f16* __restrict__ hp,
                                                   const float* __restrict__ sums,
                                                   const float* __restrict__ cnt,
                                                   const float* __restrict__ ch,
                                                   const float* __restrict__ gWih,
                                                   const float* __restrict__ gbih,
                                                   const float* __restrict__ gWhh,
                                                   const float* __restrict__ gbhh,
                                                   const float* __restrict__ Wp,
                                                   const float* __restrict__ bp,
                                                   float* __restrict__ out_uch,
                                                   float* __restrict__ c2n) {
  const int b = blockIdx.x, t = threadIdx.x;
  if (b < 1024) {                       // ---- split-K merge -> hp16 [4096][1024]
    __shared__ float wm[NSPLIT][64], wl[NSPLIT][64];
    __shared__ float tile[64][65];
    const int q0 = (b & 63) * 64, jb = (b >> 6) * 64;
    const int h  = jb >> 8;

    if (t < 64) {
#pragma unroll
      for (int s = 0; s < NSPLIT; ++s) {
        wm[s][t] = pM[(s * 4 + h) * 4096 + q0 + t];
        wl[s][t] = pL[(s * 4 + h) * 4096 + q0 + t];
      }
    }
    __syncthreads();

    const int q8 = (t & 7) * 8;
#pragma unroll
    for (int it = 0; it < 2; ++it) {
      int jl = (t >> 3) + it * 32;
      float wgt[NSPLIT][8], inv[8];
#pragma unroll
      for (int q = 0; q < 8; ++q) {
        float M = wm[0][q8 + q];
#pragma unroll
        for (int s = 1; s < NSPLIT; ++s) M = fmaxf(M, wm[s][q8 + q]);
        float den = 0.f;
#pragma unroll
        for (int s = 0; s < NSPLIT; ++s) {
          float wv = wl[s][q8 + q] * __expf(wm[s][q8 + q] - M);
          wgt[s][q] = wv; den += wv;
        }
        inv[q] = 1.f / den;
      }
      float o[8] = {0.f};
#pragma unroll
      for (int s = 0; s < NSPLIT; ++s) {
        union { uint4 u; f16 h8[8]; } raw;
        raw.u = *(const uint4*)&pO[(size_t)(s * 1024 + jb + jl) * 4096 + q0 + q8];
#pragma unroll
        for (int q = 0; q < 8; ++q) o[q] += wgt[s][q] * (float)raw.h8[q];
      }
#pragma unroll
      for (int q = 0; q < 8; ++q) tile[q8 + q][jl] = o[q] * inv[q];
    }
    __syncthreads();

#pragma unroll
    for (int it = 0; it < 2; ++it) {
      int ql = (t >> 3) + it * 32, chk = t & 7;
      union { uint4 u; f16 h8[8]; } pk;
#pragma unroll
      for (int k = 0; k < 8; ++k) pk.h8[k] = (f16)tile[ql][chk * 8 + k];
      *(uint4*)&hp[(size_t)(q0 + ql) * 1024 + jb + chk * 8] = pk.u;
    }
  } else {                              // ---- GRU + c2n, 2 clusters per block
    __shared__ float ax[2][128], hx[2][128], ul[2][128];
    const int cc = t >> 7, d = t & 127;
    const int c  = (b - 1024) * 2 + cc;
    float count = cnt[c];
    ax[cc][d] = sums[c * 128 + d] / fmaxf(count, 1.0f);
    hx[cc][d] = ch[c * 128 + d];
    __syncthreads();
    float gi[3], gh[3];
#pragma unroll
    for (int g = 0; g < 3; ++g) {
      const float4* wi4 = (const float4*)&gWih[(size_t)(g * 128 + d) * 128];
      const float4* wh4 = (const float4*)&gWhh[(size_t)(g * 128 + d) * 128];
      float si = 0.f, sh = 0.f;
#pragma unroll 8
      for (int e = 0; e < 32; ++e) {
        float4 wv = wi4[e], hv = wh4[e];
        si = fmaf(ax[cc][e*4+0], wv.x, si); si = fmaf(ax[cc][e*4+1], wv.y, si);
        si = fmaf(ax[cc][e*4+2], wv.z, si); si = fmaf(ax[cc][e*4+3], wv.w, si);
        sh = fmaf(hx[cc][e*4+0], hv.x, sh); sh = fmaf(hx[cc][e*4+1], hv.y, sh);
        sh = fmaf(hx[cc][e*4+2], hv.z, sh); sh = fmaf(hx[cc][e*4+3], hv.w, sh);
      }
      gi[g] = si + gbih[g * 128 + d];
      gh[g] = sh + gbhh[g * 128 + d];
    }
    float r = 1.f / (1.f + expf(-(gi[0] + gh[0])));
    float z = 1.f / (1.f + expf(-(gi[1] + gh[1])));
    float nn = tanhf(gi[2] + r * gh[2]);
    float hv = hx[cc][d];
    float nh = (1.f - z) * nn + z * hv;
    float res = (count > 0.f) ? nh : hv;
    ul[cc][d] = res;
    out_uch[c * 128 + d] = res;
    __syncthreads();
    const float4* w4 = (const float4*)&Wp[(size_t)d * 128];
    float s = 0.f;
#pragma unroll 8
    for (int e = 0; e < 32; ++e) {
      float4 wv = w4[e];
      s = fmaf(ul[cc][e*4+0], wv.x, s); s = fmaf(ul[cc][e*4+1], wv.y, s);
      s = fmaf(ul[cc][e*4+2], wv.z, s); s = fmaf(ul[cc][e*4+3], wv.w, s);
    }
    c2n[c * 128 + d] = s + bp[d];
  }
}

// ---------------------------------------------------------------- launch
extern "C" void kernel_launch(void* const* d_in, const int* in_sizes, int n_in,
                              void* d_out, int out_size, void* d_ws, size_t ws_size,
                              hipStream_t stream) {
  const float* x    = (const float*)d_in[0];
  const float* h    = (const float*)d_in[1];
  const float* ch   = (const float*)d_in[2];
  const int*   lab  = (const int*)d_in[4];
  const float* Wq   = (const float*)d_in[8];
  const float* bq   = (const float*)d_in[9];
  const float* Wk   = (const float*)d_in[10];
  const float* bk   = (const float*)d_in[11];
  const float* Wv   = (const float*)d_in[12];
  const float* bv   = (const float*)d_in[13];
  const float* W1   = (const float*)d_in[14];
  const float* b1   = (const float*)d_in[15];
  const float* W2   = (const float*)d_in[16];
  const float* b2   = (const float*)d_in[17];
  const float* gWih = (const float*)d_in[18];
  const float* gbih = (const float*)d_in[19];
  const float* gWhh = (const float*)d_in[20];
  const float* gbhh = (const float*)d_in[21];
  const float* Wp   = (const float*)d_in[22];
  const float* bp   = (const float*)d_in[23];

  float* outp    = (float*)d_out;                 // [4096*128] updated_h
  float* out_uch = outp + 4096 * 128;             // [64*128] updated_cluster_h

  // ---- workspace layout
  f16* comb16 = (f16*)d_ws;                        // 4096*256
  f16* w16    = comb16 + 4096 * 256;               // 655360
  f16* wq16   = w16;                               //  32768
  f16* wk16   = w16 + 32768;
  f16* wv16   = w16 + 65536;                       // 262144 [1024][256]
  f16* w116   = w16 + 327680;                      // 262144 [256][1024]
  f16* w216   = w16 + 589824;                      //  65536 [256][256]
  f16* qf16   = w16 + 655360;                      // 4096*128
  f16* kf16   = qf16 + 4096 * 128;                 // 4096*128
  f16* vt16   = kf16 + 4096 * 128;                 // 1024*4096
  f16* pO     = vt16 + 1024 * 4096;                // 4*1024*4096
  f16* hp16   = pO + (size_t)NSPLIT * 1024 * 4096; // 4096*1024
  f16* y116   = hp16 + (size_t)4096 * 1024;        // 4096*256
  float* pM   = (float*)(y116 + 4096 * 256);       // 4*4*4096
  float* pL   = pM + NSPLIT * 4 * 4096;
  float* sums = pL + NSPLIT * 4 * 4096;            // 8192 (+64 cnt contiguous)
  float* cnt  = sums + 64 * 128;                   // 64
  float* c2n  = cnt + 64;                          // 8192

  const float qscale = 0.17677669529663687f;       // 1/sqrt(32)

  // 1) combined(f16) + weights->f16 + zero(sums,cnt)
  k_prep<<<1697, 256, 0, stream>>>(x, h, Wq, Wk, Wv, W1, W2, comb16, w16, sums);
  // 2) V^T | Q | K projections + segsum, all concurrent
  k_qkv<<<3328, 256, 0, stream>>>(comb16, wq16, wk16, wv16, bq, bk, bv,
                                  qf16, kf16, vt16, h, lab, sums, cnt, qscale);
  // 3) flash attention (split-K)
  k_attn_mfma<<<dim3(64, NHEADS, NSPLIT), 256, 0, stream>>>(qf16, kf16, vt16, pO, pM, pL);
  // 4) merge -> hp16 [4096][1024]  |  GRU->c2n (also writes out_uch)
  k_mergeplus<<<1056, 256, 0, stream>>>(pO, pM, pL, hp16, sums, cnt, ch,
                                        gWih, gbih, gWhh, gbhh, Wp, bp, out_uch, c2n);
  // 5) MLP1
  k_gemm16<1><<<dim3(64, 4), 256, 0, stream>>>(hp16, w116, b1, nullptr, nullptr, nullptr,
                                               y116, 4096, 1024, 256, 1.0f);
  // 6) MLP2 (cols 128..255) fused with +h resid and +c2n[lab] -> final output
  k_gemm16<3><<<dim3(64, 2), 256, 0, stream>>>(y116, w216 + 128 * 256, b2 + 128, h, lab, c2n,
                                               outp, 4096, 256, 128, 1.0f);
}